// Round 5
// baseline (374.334 us; speedup 1.0000x reference)
//
#include <hip/hip_runtime.h>

#define NN 384
#define DM 256
#define NH 4
#define FF 1024
#define HIDN 512
#define NCLS 56
#define NPAIR (NN*(NN-1))   // 147072

typedef __attribute__((ext_vector_type(8))) short short8v;
typedef __attribute__((ext_vector_type(4))) float f32x4;
typedef __attribute__((ext_vector_type(8))) unsigned short ushort8;
typedef __attribute__((ext_vector_type(4))) unsigned int uint4v;

static __device__ __forceinline__ unsigned short f2bf(float f) {
  unsigned u = __float_as_uint(f);
  unsigned r = u + 0x7fff + ((u >> 16) & 1);   // RNE
  return (unsigned short)(r >> 16);
}
static __device__ __forceinline__ float bf2f(unsigned short v) {
  return __uint_as_float(((unsigned)v) << 16);
}
static __device__ __forceinline__ unsigned cvt_pk_bf16(float lo, float hi) {
  unsigned r;
  asm("v_cvt_pk_bf16_f32 %0, %1, %2" : "=v"(r) : "v"(lo), "v"(hi));
  return r;
}

// ---------------- tiled f32 GEMM 64x64: C = alpha*(A@B) + bias, opt relu ---
__global__ __launch_bounds__(256)
void gemm_tile(const float* __restrict__ A, int lda, long sA,
               const float* __restrict__ B, int ldb, long sB,
               const float* __restrict__ bias,
               float* __restrict__ C, int ldc, long sC,
               int K, float alpha, int relu) {
  __shared__ float As[16][64];
  __shared__ float Bs[16][64];
  A += (size_t)blockIdx.z * sA;
  B += (size_t)blockIdx.z * sB;
  C += (size_t)blockIdx.z * sC;
  int tid = threadIdx.x;
  int tx = tid & 15;
  int ty = tid >> 4;
  int m0 = blockIdx.y * 64;
  int n0 = blockIdx.x * 64;
  int la_r = tid >> 2;
  int la_k = (tid & 3) * 4;
  int lb_k = tid >> 4;
  int lb_n = (tid & 15) * 4;

  float acc[4][4] = {};
  float4 av = *reinterpret_cast<const float4*>(A + (size_t)(m0 + la_r) * lda + la_k);
  float4 bv = *reinterpret_cast<const float4*>(B + (size_t)lb_k * ldb + n0 + lb_n);
  int nchunk = K >> 4;
  for (int ch = 0; ch < nchunk; ++ch) {
    __syncthreads();
    As[la_k + 0][la_r] = av.x;
    As[la_k + 1][la_r] = av.y;
    As[la_k + 2][la_r] = av.z;
    As[la_k + 3][la_r] = av.w;
    *reinterpret_cast<float4*>(&Bs[lb_k][lb_n]) = bv;
    if (ch + 1 < nchunk) {
      int k0 = (ch + 1) << 4;
      av = *reinterpret_cast<const float4*>(A + (size_t)(m0 + la_r) * lda + k0 + la_k);
      bv = *reinterpret_cast<const float4*>(B + (size_t)(k0 + lb_k) * ldb + n0 + lb_n);
    }
    __syncthreads();
    #pragma unroll
    for (int k = 0; k < 16; ++k) {
      float4 a4 = *reinterpret_cast<const float4*>(&As[k][ty * 4]);
      float4 b4 = *reinterpret_cast<const float4*>(&Bs[k][tx * 4]);
      acc[0][0] += a4.x * b4.x; acc[0][1] += a4.x * b4.y; acc[0][2] += a4.x * b4.z; acc[0][3] += a4.x * b4.w;
      acc[1][0] += a4.y * b4.x; acc[1][1] += a4.y * b4.y; acc[1][2] += a4.y * b4.z; acc[1][3] += a4.y * b4.w;
      acc[2][0] += a4.z * b4.x; acc[2][1] += a4.z * b4.y; acc[2][2] += a4.z * b4.z; acc[2][3] += a4.z * b4.w;
      acc[3][0] += a4.w * b4.x; acc[3][1] += a4.w * b4.y; acc[3][2] += a4.w * b4.z; acc[3][3] += a4.w * b4.w;
    }
  }
  float4 bb = make_float4(0.f, 0.f, 0.f, 0.f);
  if (bias) bb = *reinterpret_cast<const float4*>(bias + n0 + tx * 4);
  #pragma unroll
  for (int i = 0; i < 4; ++i) {
    float4 r;
    r.x = acc[i][0] * alpha + bb.x;
    r.y = acc[i][1] * alpha + bb.y;
    r.z = acc[i][2] * alpha + bb.z;
    r.w = acc[i][3] * alpha + bb.w;
    if (relu) {
      r.x = fmaxf(r.x, 0.f); r.y = fmaxf(r.y, 0.f);
      r.z = fmaxf(r.z, 0.f); r.w = fmaxf(r.w, 0.f);
    }
    *reinterpret_cast<float4*>(C + (size_t)(m0 + ty * 4 + i) * ldc + n0 + tx * 4) = r;
  }
}

// ---------------- tiled f32 GEMM 32x32 (more blocks for small outputs) ----
__global__ __launch_bounds__(256)
void gemm32(const float* __restrict__ A, int lda, long sA,
            const float* __restrict__ B, int ldb, long sB,
            const float* __restrict__ bias,
            float* __restrict__ C, int ldc, long sC,
            int K, float alpha, int relu) {
  __shared__ float As[16][33];
  __shared__ float Bs[16][33];
  A += (size_t)blockIdx.z * sA;
  B += (size_t)blockIdx.z * sB;
  C += (size_t)blockIdx.z * sC;
  int tid = threadIdx.x;
  int tx = tid & 15;
  int ty = tid >> 4;
  int m0 = blockIdx.y * 32;
  int n0 = blockIdx.x * 32;
  float acc[2][2] = {};
  int ar = (tid & 127) >> 2;
  int ak = (tid & 3) * 4;
  int bk = (tid & 127) >> 3;
  int bn = ((tid & 127) & 7) * 4;
  bool doA = tid < 128;
  float4 pre;
  if (doA) pre = *reinterpret_cast<const float4*>(A + (size_t)(m0 + ar) * lda + ak);
  else     pre = *reinterpret_cast<const float4*>(B + (size_t)bk * ldb + n0 + bn);
  int nchunk = K >> 4;
  for (int ch = 0; ch < nchunk; ++ch) {
    __syncthreads();
    if (doA) {
      As[ak + 0][ar] = pre.x; As[ak + 1][ar] = pre.y;
      As[ak + 2][ar] = pre.z; As[ak + 3][ar] = pre.w;
    } else {
      Bs[bk][bn + 0] = pre.x; Bs[bk][bn + 1] = pre.y;
      Bs[bk][bn + 2] = pre.z; Bs[bk][bn + 3] = pre.w;
    }
    if (ch + 1 < nchunk) {
      int k0 = (ch + 1) << 4;
      if (doA) pre = *reinterpret_cast<const float4*>(A + (size_t)(m0 + ar) * lda + k0 + ak);
      else     pre = *reinterpret_cast<const float4*>(B + (size_t)(k0 + bk) * ldb + n0 + bn);
    }
    __syncthreads();
    #pragma unroll
    for (int k = 0; k < 16; ++k) {
      float a0 = As[k][ty * 2], a1 = As[k][ty * 2 + 1];
      float b0 = Bs[k][tx * 2], b1 = Bs[k][tx * 2 + 1];
      acc[0][0] += a0 * b0; acc[0][1] += a0 * b1;
      acc[1][0] += a1 * b0; acc[1][1] += a1 * b1;
    }
  }
  float bb0 = 0.f, bb1 = 0.f;
  if (bias) { bb0 = bias[n0 + tx * 2]; bb1 = bias[n0 + tx * 2 + 1]; }
  #pragma unroll
  for (int r = 0; r < 2; ++r) {
    float v0 = acc[r][0] * alpha + bb0;
    float v1 = acc[r][1] * alpha + bb1;
    if (relu) { v0 = fmaxf(v0, 0.f); v1 = fmaxf(v1, 0.f); }
    float2 st = make_float2(v0, v1);
    *reinterpret_cast<float2*>(C + (size_t)(m0 + ty * 2 + r) * ldc + n0 + tx * 2) = st;
  }
}

// ---------------- transpose K heads ---------------------------------------
__global__ __launch_bounds__(256)
void transpose_k(const float* __restrict__ qkv, float* __restrict__ kt) {
  int idx = blockIdx.x * 256 + threadIdx.x;
  int m = idx % NN;
  int d = (idx / NN) & 63;
  int h = idx / (NN * 64);
  kt[idx] = qkv[(size_t)m * 768 + 256 + h * 64 + d];
}

// ---------------- row softmax over 384 ------------------------------------
__global__ __launch_bounds__(128)
void softmax_rows(float* __restrict__ sc) {
  float* row = sc + (size_t)blockIdx.x * NN;
  int t = threadIdx.x;
  float v0 = row[t], v1 = row[t + 128], v2 = row[t + 256];
  __shared__ float red[128];
  float m = fmaxf(v0, fmaxf(v1, v2));
  red[t] = m; __syncthreads();
  for (int s = 64; s > 0; s >>= 1) { if (t < s) red[t] = fmaxf(red[t], red[t + s]); __syncthreads(); }
  m = red[0]; __syncthreads();
  float e0 = expf(v0 - m), e1 = expf(v1 - m), e2 = expf(v2 - m);
  red[t] = e0 + e1 + e2; __syncthreads();
  for (int s = 64; s > 0; s >>= 1) { if (t < s) red[t] += red[t + s]; __syncthreads(); }
  float inv = 1.0f / red[0];
  row[t] = e0 * inv; row[t + 128] = e1 * inv; row[t + 256] = e2 * inv;
}

// ---------------- residual add + LayerNorm --------------------------------
__global__ __launch_bounds__(256)
void add_ln(float* __restrict__ x, const float* __restrict__ r,
            const float* __restrict__ g, const float* __restrict__ b) {
  int i = blockIdx.x, t = threadIdx.x;
  float v = x[(size_t)i * DM + t] + r[(size_t)i * DM + t];
  __shared__ float red[256];
  red[t] = v; __syncthreads();
  for (int s = 128; s > 0; s >>= 1) { if (t < s) red[t] += red[t + s]; __syncthreads(); }
  float mu = red[0] * (1.0f / DM); __syncthreads();
  float dv = v - mu;
  red[t] = dv * dv; __syncthreads();
  for (int s = 128; s > 0; s >>= 1) { if (t < s) red[t] += red[t + s]; __syncthreads(); }
  float var = red[0] * (1.0f / DM);
  float inv = rsqrtf(var + 1e-5f);
  x[(size_t)i * DM + t] = dv * inv * g[t] + b[t];
}

// ------ add box terms; U stays f32, V goes to global bf16 -----------------
__global__ __launch_bounds__(256)
void uv_fixup(const float* __restrict__ boxes, const float* __restrict__ w1,
              float* __restrict__ U, const float* __restrict__ V,
              unsigned short* __restrict__ Vbf) {
  int idx = blockIdx.x * 256 + threadIdx.x;   // NN*HIDN
  int i = idx >> 9, k = idx & 511;
  float u = U[idx], v = V[idx];
  #pragma unroll
  for (int c = 0; c < 4; ++c) {
    float bv = boxes[i * 4 + c];
    u += bv * w1[(size_t)(512 + c) * HIDN + k];
    v += bv * w1[(size_t)(516 + c) * HIDN + k];
  }
  U[idx] = u;
  Vbf[idx] = f2bf(v);
}

// ---------------- pack W2 into MFMA B-fragment order (bf16) ---------------
// lane l holds B[k = ks*32 + (l>>4)*8 + r][n = nt*16 + (l&15)]
__global__ __launch_bounds__(256)
void prep_w2frag(const float* __restrict__ w2, unsigned short* __restrict__ frag) {
  int idx = blockIdx.x * 256 + threadIdx.x;   // 16*4*64 = 4096
  int l = idx & 63;
  int nt = (idx >> 6) & 3;
  int ks = idx >> 8;
  int kb = ks * 32 + ((l >> 4) * 8);
  int n = nt * 16 + (l & 15);
  #pragma unroll
  for (int r = 0; r < 8; ++r) {
    float v = (n < NCLS) ? w2[(size_t)(kb + r) * NCLS + n] : 0.f;
    frag[(size_t)idx * 8 + r] = f2bf(v);
  }
}

// ---------------- pair indices output -------------------------------------
__global__ __launch_bounds__(256)
void pair_idx_kernel(float* __restrict__ out) {
  int p = blockIdx.x * 256 + threadIdx.x;
  if (p >= NPAIR) return;
  int i = p / (NN - 1);
  int r = p - i * (NN - 1);
  int j = r + (r >= i ? 1 : 0);
  out[2 * p + 0] = (float)i;
  out[2 * p + 1] = (float)j;
}

// ---------------- pair MLP via MFMA v3: barrier-free, register-built A ----
// Wave task: (j-tile of 16, class-tile pair), loop over 6 i's.
// A-frag built in registers: lane l -> A[jt*16 + (l&15)][ks*32 + (l>>4)*8 + r]
//  = relu(Vbf[j][k] + U[i][k]).  V-frags resident (64 VGPR); U via L1-broadcast
// loads (4 distinct 32B segments per wave). No LDS, no barriers.
__global__ __launch_bounds__(256)
void pair_mfma(const float* __restrict__ U, const unsigned short* __restrict__ Vbf,
               const unsigned short* __restrict__ w2frag,
               const float* __restrict__ b2, float* __restrict__ out) {
  int tid = threadIdx.x;
  int wave = tid >> 6;
  int lane = tid & 63;
  int jt = blockIdx.x * 2 + (wave >> 1);     // 0..23
  int nth = wave & 1;                        // class-tile pair {2nth, 2nth+1}
  int i0 = blockIdx.y * 6;

  // B fragments resident (hopefully AGPR-allocated)
  short8v bfrag0[16], bfrag1[16];
  #pragma unroll
  for (int ks = 0; ks < 16; ++ks) {
    bfrag0[ks] = *reinterpret_cast<const short8v*>(
        w2frag + ((size_t)(ks * 4 + nth * 2 + 0) * 64 + lane) * 8);
    bfrag1[ks] = *reinterpret_cast<const short8v*>(
        w2frag + ((size_t)(ks * 4 + nth * 2 + 1) * 64 + lane) * 8);
  }

  int colc = lane & 15;
  int g = lane >> 4;
  int cls0 = nth * 32 + colc;                // < 56 always
  int cls1 = cls0 + 16;
  float b2v0 = b2[cls0];
  float b2v1 = (cls1 < NCLS) ? b2[cls1] : 0.f;

  // V fragments resident: this lane's A-row j_row, all 16 k-slices
  int j_row = jt * 16 + colc;
  ushort8 vfrag[16];
  #pragma unroll
  for (int ks = 0; ks < 16; ++ks)
    vfrag[ks] = *reinterpret_cast<const ushort8*>(
        Vbf + (size_t)j_row * HIDN + ks * 32 + g * 8);

  float* lg = out + 2 * (size_t)NPAIR;

  for (int ii = 0; ii < 6; ++ii) {
    int i = i0 + ii;
    const float* urow = U + (size_t)i * HIDN;
    f32x4 acc0 = {}, acc1 = {};
    #pragma unroll
    for (int ks = 0; ks < 16; ++ks) {
      float4 ua = *reinterpret_cast<const float4*>(urow + ks * 32 + g * 8);
      float4 ub = *reinterpret_cast<const float4*>(urow + ks * 32 + g * 8 + 4);
      ushort8 v8 = vfrag[ks];
      float h0 = fmaxf(bf2f(v8[0]) + ua.x, 0.f);
      float h1 = fmaxf(bf2f(v8[1]) + ua.y, 0.f);
      float h2 = fmaxf(bf2f(v8[2]) + ua.z, 0.f);
      float h3 = fmaxf(bf2f(v8[3]) + ua.w, 0.f);
      float h4 = fmaxf(bf2f(v8[4]) + ub.x, 0.f);
      float h5 = fmaxf(bf2f(v8[5]) + ub.y, 0.f);
      float h6 = fmaxf(bf2f(v8[6]) + ub.z, 0.f);
      float h7 = fmaxf(bf2f(v8[7]) + ub.w, 0.f);
      uint4v pk;
      pk[0] = cvt_pk_bf16(h0, h1);
      pk[1] = cvt_pk_bf16(h2, h3);
      pk[2] = cvt_pk_bf16(h4, h5);
      pk[3] = cvt_pk_bf16(h6, h7);
      short8v a = *reinterpret_cast<short8v*>(&pk);
      acc0 = __builtin_amdgcn_mfma_f32_16x16x32_bf16(a, bfrag0[ks], acc0, 0, 0, 0);
      acc1 = __builtin_amdgcn_mfma_f32_16x16x32_bf16(a, bfrag1[ks], acc1, 0, 0, 0);
    }
    #pragma unroll
    for (int r = 0; r < 4; ++r) {
      int j = jt * 16 + g * 4 + r;
      if (j == i) continue;
      int p = i * (NN - 1) + (j > i ? j - 1 : j);
      lg[(size_t)p * NCLS + cls0] = acc0[r] + b2v0;
      if (cls1 < NCLS) lg[(size_t)p * NCLS + cls1] = acc1[r] + b2v1;
    }
  }
}

// --------------------------------------------------------------------------
extern "C" void kernel_launch(void* const* d_in, const int* in_sizes, int n_in,
                              void* d_out, int out_size, void* d_ws, size_t ws_size,
                              hipStream_t stream) {
  const float* node   = (const float*)d_in[0];
  const float* boxes  = (const float*)d_in[1];
  const float* w_in   = (const float*)d_in[2];
  const float* b_in   = (const float*)d_in[3];
  const float* w_out  = (const float*)d_in[4];
  const float* b_out  = (const float*)d_in[5];
  const float* fw1    = (const float*)d_in[6];
  const float* fb1    = (const float*)d_in[7];
  const float* fw2    = (const float*)d_in[8];
  const float* fb2    = (const float*)d_in[9];
  const float* ln1g   = (const float*)d_in[10];
  const float* ln1b   = (const float*)d_in[11];
  const float* ln2g   = (const float*)d_in[12];
  const float* ln2b   = (const float*)d_in[13];
  const float* mw1    = (const float*)d_in[14];
  const float* mb1    = (const float*)d_in[15];
  const float* mw2    = (const float*)d_in[16];
  const float* mb2    = (const float*)d_in[17];
  float* out = (float*)d_out;

  float* ws = (float*)d_ws;
  float* xbuf  = ws;                   // 384*256
  float* qkv   = xbuf  + 98304;        // 384*768
  float* sc    = qkv   + 294912;       // 4*384*384
  float* attno = sc    + 589824;       // 384*256
  float* proj  = attno + 98304;        // 384*256
  float* ffh   = proj  + 98304;        // 384*1024
  float* U     = ffh   + 393216;       // 384*512
  float* V     = U     + 196608;       // 384*512
  unsigned short* Vbf    = (unsigned short*)(V + 196608);    // 384*512 bf16
  unsigned short* w2frag = (unsigned short*)(V + 294912);    // 64KB
  float* kt    = V + 327680;                                 // 4*64*384

  hipMemcpyAsync(xbuf, node, (size_t)NN * DM * sizeof(float),
                 hipMemcpyDeviceToDevice, stream);
  prep_w2frag<<<dim3(16), 256, 0, stream>>>(mw2, w2frag);
  pair_idx_kernel<<<dim3((NPAIR + 255) / 256), 256, 0, stream>>>(out);

  for (int l = 0; l < 2; ++l) {
    const float* wi  = w_in  + (size_t)l * DM * 768;
    const float* bi  = b_in  + (size_t)l * 768;
    const float* wo  = w_out + (size_t)l * DM * DM;
    const float* bo  = b_out + (size_t)l * DM;
    const float* w1l = fw1   + (size_t)l * DM * FF;
    const float* b1l = fb1   + (size_t)l * FF;
    const float* w2l = fw2   + (size_t)l * FF * DM;
    const float* b2l = fb2   + (size_t)l * DM;

    gemm_tile<<<dim3(12, 6, 1), 256, 0, stream>>>(xbuf, DM, 0, wi, 768, 0, bi,
                                                  qkv, 768, 0, DM, 1.f, 0);
    transpose_k<<<dim3(384), 256, 0, stream>>>(qkv, kt);
    gemm_tile<<<dim3(6, 6, NH), 256, 0, stream>>>(qkv, 768, 64, kt, NN, 64 * NN,
                                                  nullptr, sc, NN, (long)NN * NN,
                                                  64, 0.125f, 0);
    softmax_rows<<<dim3(NH * NN), 128, 0, stream>>>(sc);
    gemm32<<<dim3(2, 12, NH), 256, 0, stream>>>(sc, NN, (long)NN * NN,
                                                qkv + 512, 768, 64, nullptr,
                                                attno, DM, 64, NN, 1.f, 0);
    gemm32<<<dim3(8, 12, 1), 256, 0, stream>>>(attno, DM, 0, wo, DM, 0, bo,
                                               proj, DM, 0, DM, 1.f, 0);
    add_ln<<<dim3(NN), 256, 0, stream>>>(xbuf, proj, ln1g + (size_t)l * DM, ln1b + (size_t)l * DM);
    gemm_tile<<<dim3(16, 6, 1), 256, 0, stream>>>(xbuf, DM, 0, w1l, FF, 0, b1l,
                                                  ffh, FF, 0, DM, 1.f, 1);
    gemm32<<<dim3(8, 12, 1), 256, 0, stream>>>(ffh, FF, 0, w2l, DM, 0, b2l,
                                               proj, DM, 0, FF, 1.f, 0);
    add_ln<<<dim3(NN), 256, 0, stream>>>(xbuf, proj, ln2g + (size_t)l * DM, ln2b + (size_t)l * DM);
  }

  // relation MLP: U = x@W1[0:256]+b1, V = x@W1[256:512], then box/bf16 fixup
  gemm_tile<<<dim3(8, 6, 1), 256, 0, stream>>>(xbuf, DM, 0, mw1, HIDN, 0, mb1,
                                               U, HIDN, 0, DM, 1.f, 0);
  gemm_tile<<<dim3(8, 6, 1), 256, 0, stream>>>(xbuf, DM, 0, mw1 + (size_t)DM * HIDN,
                                               HIDN, 0, nullptr, V, HIDN, 0, DM, 1.f, 0);
  uv_fixup<<<dim3(NN * HIDN / 256), 256, 0, stream>>>(boxes, mw1, U, V, Vbf);
  // pair GEMM: barrier-free wave-independent MFMA
  pair_mfma<<<dim3(12, 64), 256, 0, stream>>>(U, Vbf, w2frag, mb2, out);
}

// Round 6
// 371.357 us; speedup vs baseline: 1.0080x; 1.0080x over previous
//
#include <hip/hip_runtime.h>

#define NN 384
#define DM 256
#define NH 4
#define FF 1024
#define HIDN 512
#define NCLS 56
#define NPAIR (NN*(NN-1))   // 147072

typedef __attribute__((ext_vector_type(8))) short short8v;
typedef __attribute__((ext_vector_type(4))) float f32x4;
typedef __attribute__((ext_vector_type(8))) unsigned short ushort8;
typedef __attribute__((ext_vector_type(4))) unsigned int uint4v;

static __device__ __forceinline__ unsigned short f2bf(float f) {
  unsigned u = __float_as_uint(f);
  unsigned r = u + 0x7fff + ((u >> 16) & 1);   // RNE
  return (unsigned short)(r >> 16);
}
static __device__ __forceinline__ float bf2f(unsigned short v) {
  return __uint_as_float(((unsigned)v) << 16);
}
static __device__ __forceinline__ unsigned cvt_pk_bf16(float lo, float hi) {
  unsigned r;
  asm("v_cvt_pk_bf16_f32 %0, %1, %2" : "=v"(r) : "v"(lo), "v"(hi));
  return r;
}

// ---------------- tiled f32 GEMM 64x64: C = alpha*(A@B) + bias, opt relu ---
__global__ __launch_bounds__(256)
void gemm_tile(const float* __restrict__ A, int lda, long sA,
               const float* __restrict__ B, int ldb, long sB,
               const float* __restrict__ bias,
               float* __restrict__ C, int ldc, long sC,
               int K, float alpha, int relu) {
  __shared__ float As[16][64];
  __shared__ float Bs[16][64];
  A += (size_t)blockIdx.z * sA;
  B += (size_t)blockIdx.z * sB;
  C += (size_t)blockIdx.z * sC;
  int tid = threadIdx.x;
  int tx = tid & 15;
  int ty = tid >> 4;
  int m0 = blockIdx.y * 64;
  int n0 = blockIdx.x * 64;
  int la_r = tid >> 2;
  int la_k = (tid & 3) * 4;
  int lb_k = tid >> 4;
  int lb_n = (tid & 15) * 4;

  float acc[4][4] = {};
  float4 av = *reinterpret_cast<const float4*>(A + (size_t)(m0 + la_r) * lda + la_k);
  float4 bv = *reinterpret_cast<const float4*>(B + (size_t)lb_k * ldb + n0 + lb_n);
  int nchunk = K >> 4;
  for (int ch = 0; ch < nchunk; ++ch) {
    __syncthreads();
    As[la_k + 0][la_r] = av.x;
    As[la_k + 1][la_r] = av.y;
    As[la_k + 2][la_r] = av.z;
    As[la_k + 3][la_r] = av.w;
    *reinterpret_cast<float4*>(&Bs[lb_k][lb_n]) = bv;
    if (ch + 1 < nchunk) {
      int k0 = (ch + 1) << 4;
      av = *reinterpret_cast<const float4*>(A + (size_t)(m0 + la_r) * lda + k0 + la_k);
      bv = *reinterpret_cast<const float4*>(B + (size_t)(k0 + lb_k) * ldb + n0 + lb_n);
    }
    __syncthreads();
    #pragma unroll
    for (int k = 0; k < 16; ++k) {
      float4 a4 = *reinterpret_cast<const float4*>(&As[k][ty * 4]);
      float4 b4 = *reinterpret_cast<const float4*>(&Bs[k][tx * 4]);
      acc[0][0] += a4.x * b4.x; acc[0][1] += a4.x * b4.y; acc[0][2] += a4.x * b4.z; acc[0][3] += a4.x * b4.w;
      acc[1][0] += a4.y * b4.x; acc[1][1] += a4.y * b4.y; acc[1][2] += a4.y * b4.z; acc[1][3] += a4.y * b4.w;
      acc[2][0] += a4.z * b4.x; acc[2][1] += a4.z * b4.y; acc[2][2] += a4.z * b4.z; acc[2][3] += a4.z * b4.w;
      acc[3][0] += a4.w * b4.x; acc[3][1] += a4.w * b4.y; acc[3][2] += a4.w * b4.z; acc[3][3] += a4.w * b4.w;
    }
  }
  float4 bb = make_float4(0.f, 0.f, 0.f, 0.f);
  if (bias) bb = *reinterpret_cast<const float4*>(bias + n0 + tx * 4);
  #pragma unroll
  for (int i = 0; i < 4; ++i) {
    float4 r;
    r.x = acc[i][0] * alpha + bb.x;
    r.y = acc[i][1] * alpha + bb.y;
    r.z = acc[i][2] * alpha + bb.z;
    r.w = acc[i][3] * alpha + bb.w;
    if (relu) {
      r.x = fmaxf(r.x, 0.f); r.y = fmaxf(r.y, 0.f);
      r.z = fmaxf(r.z, 0.f); r.w = fmaxf(r.w, 0.f);
    }
    *reinterpret_cast<float4*>(C + (size_t)(m0 + ty * 4 + i) * ldc + n0 + tx * 4) = r;
  }
}

// ---------------- tiled f32 GEMM 32x32 (more blocks for small outputs) ----
__global__ __launch_bounds__(256)
void gemm32(const float* __restrict__ A, int lda, long sA,
            const float* __restrict__ B, int ldb, long sB,
            const float* __restrict__ bias,
            float* __restrict__ C, int ldc, long sC,
            int K, float alpha, int relu) {
  __shared__ float As[16][33];
  __shared__ float Bs[16][33];
  A += (size_t)blockIdx.z * sA;
  B += (size_t)blockIdx.z * sB;
  C += (size_t)blockIdx.z * sC;
  int tid = threadIdx.x;
  int tx = tid & 15;
  int ty = tid >> 4;
  int m0 = blockIdx.y * 32;
  int n0 = blockIdx.x * 32;
  float acc[2][2] = {};
  int ar = (tid & 127) >> 2;
  int ak = (tid & 3) * 4;
  int bk = (tid & 127) >> 3;
  int bn = ((tid & 127) & 7) * 4;
  bool doA = tid < 128;
  float4 pre;
  if (doA) pre = *reinterpret_cast<const float4*>(A + (size_t)(m0 + ar) * lda + ak);
  else     pre = *reinterpret_cast<const float4*>(B + (size_t)bk * ldb + n0 + bn);
  int nchunk = K >> 4;
  for (int ch = 0; ch < nchunk; ++ch) {
    __syncthreads();
    if (doA) {
      As[ak + 0][ar] = pre.x; As[ak + 1][ar] = pre.y;
      As[ak + 2][ar] = pre.z; As[ak + 3][ar] = pre.w;
    } else {
      Bs[bk][bn + 0] = pre.x; Bs[bk][bn + 1] = pre.y;
      Bs[bk][bn + 2] = pre.z; Bs[bk][bn + 3] = pre.w;
    }
    if (ch + 1 < nchunk) {
      int k0 = (ch + 1) << 4;
      if (doA) pre = *reinterpret_cast<const float4*>(A + (size_t)(m0 + ar) * lda + k0 + ak);
      else     pre = *reinterpret_cast<const float4*>(B + (size_t)(k0 + bk) * ldb + n0 + bn);
    }
    __syncthreads();
    #pragma unroll
    for (int k = 0; k < 16; ++k) {
      float a0 = As[k][ty * 2], a1 = As[k][ty * 2 + 1];
      float b0 = Bs[k][tx * 2], b1 = Bs[k][tx * 2 + 1];
      acc[0][0] += a0 * b0; acc[0][1] += a0 * b1;
      acc[1][0] += a1 * b0; acc[1][1] += a1 * b1;
    }
  }
  float bb0 = 0.f, bb1 = 0.f;
  if (bias) { bb0 = bias[n0 + tx * 2]; bb1 = bias[n0 + tx * 2 + 1]; }
  #pragma unroll
  for (int r = 0; r < 2; ++r) {
    float v0 = acc[r][0] * alpha + bb0;
    float v1 = acc[r][1] * alpha + bb1;
    if (relu) { v0 = fmaxf(v0, 0.f); v1 = fmaxf(v1, 0.f); }
    float2 st = make_float2(v0, v1);
    *reinterpret_cast<float2*>(C + (size_t)(m0 + ty * 2 + r) * ldc + n0 + tx * 2) = st;
  }
}

// ---------------- transpose K heads ---------------------------------------
__global__ __launch_bounds__(256)
void transpose_k(const float* __restrict__ qkv, float* __restrict__ kt) {
  int idx = blockIdx.x * 256 + threadIdx.x;
  int m = idx % NN;
  int d = (idx / NN) & 63;
  int h = idx / (NN * 64);
  kt[idx] = qkv[(size_t)m * 768 + 256 + h * 64 + d];
}

// ---------------- row softmax over 384 ------------------------------------
__global__ __launch_bounds__(128)
void softmax_rows(float* __restrict__ sc) {
  float* row = sc + (size_t)blockIdx.x * NN;
  int t = threadIdx.x;
  float v0 = row[t], v1 = row[t + 128], v2 = row[t + 256];
  __shared__ float red[128];
  float m = fmaxf(v0, fmaxf(v1, v2));
  red[t] = m; __syncthreads();
  for (int s = 64; s > 0; s >>= 1) { if (t < s) red[t] = fmaxf(red[t], red[t + s]); __syncthreads(); }
  m = red[0]; __syncthreads();
  float e0 = expf(v0 - m), e1 = expf(v1 - m), e2 = expf(v2 - m);
  red[t] = e0 + e1 + e2; __syncthreads();
  for (int s = 64; s > 0; s >>= 1) { if (t < s) red[t] += red[t + s]; __syncthreads(); }
  float inv = 1.0f / red[0];
  row[t] = e0 * inv; row[t + 128] = e1 * inv; row[t + 256] = e2 * inv;
}

// ---------------- residual add + LayerNorm --------------------------------
__global__ __launch_bounds__(256)
void add_ln(float* __restrict__ x, const float* __restrict__ r,
            const float* __restrict__ g, const float* __restrict__ b) {
  int i = blockIdx.x, t = threadIdx.x;
  float v = x[(size_t)i * DM + t] + r[(size_t)i * DM + t];
  __shared__ float red[256];
  red[t] = v; __syncthreads();
  for (int s = 128; s > 0; s >>= 1) { if (t < s) red[t] += red[t + s]; __syncthreads(); }
  float mu = red[0] * (1.0f / DM); __syncthreads();
  float dv = v - mu;
  red[t] = dv * dv; __syncthreads();
  for (int s = 128; s > 0; s >>= 1) { if (t < s) red[t] += red[t + s]; __syncthreads(); }
  float var = red[0] * (1.0f / DM);
  float inv = rsqrtf(var + 1e-5f);
  x[(size_t)i * DM + t] = dv * inv * g[t] + b[t];
}

// ------ add box terms; U stays f32, V goes to global bf16 -----------------
__global__ __launch_bounds__(256)
void uv_fixup(const float* __restrict__ boxes, const float* __restrict__ w1,
              float* __restrict__ U, const float* __restrict__ V,
              unsigned short* __restrict__ Vbf) {
  int idx = blockIdx.x * 256 + threadIdx.x;   // NN*HIDN
  int i = idx >> 9, k = idx & 511;
  float u = U[idx], v = V[idx];
  #pragma unroll
  for (int c = 0; c < 4; ++c) {
    float bv = boxes[i * 4 + c];
    u += bv * w1[(size_t)(512 + c) * HIDN + k];
    v += bv * w1[(size_t)(516 + c) * HIDN + k];
  }
  U[idx] = u;
  Vbf[idx] = f2bf(v);
}

// ---------------- pack W2 into MFMA B-fragment order (bf16) ---------------
// lane l holds B[k = ks*32 + (l>>4)*8 + r][n = nt*16 + (l&15)]
__global__ __launch_bounds__(256)
void prep_w2frag(const float* __restrict__ w2, unsigned short* __restrict__ frag) {
  int idx = blockIdx.x * 256 + threadIdx.x;   // 16*4*64 = 4096
  int l = idx & 63;
  int nt = (idx >> 6) & 3;
  int ks = idx >> 8;
  int kb = ks * 32 + ((l >> 4) * 8);
  int n = nt * 16 + (l & 15);
  #pragma unroll
  for (int r = 0; r < 8; ++r) {
    float v = (n < NCLS) ? w2[(size_t)(kb + r) * NCLS + n] : 0.f;
    frag[(size_t)idx * 8 + r] = f2bf(v);
  }
}

// ---------------- pair indices output -------------------------------------
__global__ __launch_bounds__(256)
void pair_idx_kernel(float* __restrict__ out) {
  int p = blockIdx.x * 256 + threadIdx.x;
  if (p >= NPAIR) return;
  int i = p / (NN - 1);
  int r = p - i * (NN - 1);
  int j = r + (r >= i ? 1 : 0);
  out[2 * p + 0] = (float)i;
  out[2 * p + 1] = (float)j;
}

// ---------------- pair MLP via MFMA v4: 1 class-tile/wave, frags resident -
// Wave task: (jt of 16 j's, class-tile nt, 4 i's). bfrag 64 VGPR + vfrag 64
// VGPR, __launch_bounds__(256,2) allows 256 VGPR so both stay resident.
// Inner loop per i: only U loads (L1-broadcast, 4 distinct 32B/wave) +
// build (add,max,cvt_pk) + MFMA. No LDS, no barriers, no B/V reloads.
__global__ __launch_bounds__(256, 2)
void pair_mfma(const float* __restrict__ U, const unsigned short* __restrict__ Vbf,
               const unsigned short* __restrict__ w2frag,
               const float* __restrict__ b2, float* __restrict__ out) {
  int tid = threadIdx.x;
  int nth = tid >> 6;                        // class-tile 0..3 (one per wave)
  int lane = tid & 63;
  int jt = blockIdx.x;                       // 0..23
  int i0 = blockIdx.y * 4;                   // 96 i-groups

  // B fragments for this wave's class-tile: 16 ks x 4 VGPR = 64 VGPR
  short8v bfrag[16];
  #pragma unroll
  for (int ks = 0; ks < 16; ++ks)
    bfrag[ks] = *reinterpret_cast<const short8v*>(
        w2frag + ((size_t)(ks * 4 + nth) * 64 + lane) * 8);

  int colc = lane & 15;
  int g = lane >> 4;
  int cls = nth * 16 + colc;
  float b2v = (cls < NCLS) ? b2[cls] : 0.f;
  bool cls_ok = (cls < NCLS);

  // V fragments: this lane's A-row, all 16 k-slices: 64 VGPR
  int j_row = jt * 16 + colc;
  ushort8 vfrag[16];
  #pragma unroll
  for (int ks = 0; ks < 16; ++ks)
    vfrag[ks] = *reinterpret_cast<const ushort8*>(
        Vbf + (size_t)j_row * HIDN + ks * 32 + g * 8);

  float* lg = out + 2 * (size_t)NPAIR;

  for (int ii = 0; ii < 4; ++ii) {
    int i = i0 + ii;
    const float* urow = U + (size_t)i * HIDN;
    f32x4 acc = {};
    #pragma unroll
    for (int ks = 0; ks < 16; ++ks) {
      float4 ua = *reinterpret_cast<const float4*>(urow + ks * 32 + g * 8);
      float4 ub = *reinterpret_cast<const float4*>(urow + ks * 32 + g * 8 + 4);
      ushort8 v8 = vfrag[ks];
      float h0 = fmaxf(bf2f(v8[0]) + ua.x, 0.f);
      float h1 = fmaxf(bf2f(v8[1]) + ua.y, 0.f);
      float h2 = fmaxf(bf2f(v8[2]) + ua.z, 0.f);
      float h3 = fmaxf(bf2f(v8[3]) + ua.w, 0.f);
      float h4 = fmaxf(bf2f(v8[4]) + ub.x, 0.f);
      float h5 = fmaxf(bf2f(v8[5]) + ub.y, 0.f);
      float h6 = fmaxf(bf2f(v8[6]) + ub.z, 0.f);
      float h7 = fmaxf(bf2f(v8[7]) + ub.w, 0.f);
      uint4v pk;
      pk[0] = cvt_pk_bf16(h0, h1);
      pk[1] = cvt_pk_bf16(h2, h3);
      pk[2] = cvt_pk_bf16(h4, h5);
      pk[3] = cvt_pk_bf16(h6, h7);
      short8v a = *reinterpret_cast<short8v*>(&pk);
      acc = __builtin_amdgcn_mfma_f32_16x16x32_bf16(a, bfrag[ks], acc, 0, 0, 0);
    }
    if (cls_ok) {
      #pragma unroll
      for (int r = 0; r < 4; ++r) {
        int j = jt * 16 + g * 4 + r;
        if (j == i) continue;
        int p = i * (NN - 1) + (j > i ? j - 1 : j);
        lg[(size_t)p * NCLS + cls] = acc[r] + b2v;
      }
    }
  }
}

// --------------------------------------------------------------------------
extern "C" void kernel_launch(void* const* d_in, const int* in_sizes, int n_in,
                              void* d_out, int out_size, void* d_ws, size_t ws_size,
                              hipStream_t stream) {
  const float* node   = (const float*)d_in[0];
  const float* boxes  = (const float*)d_in[1];
  const float* w_in   = (const float*)d_in[2];
  const float* b_in   = (const float*)d_in[3];
  const float* w_out  = (const float*)d_in[4];
  const float* b_out  = (const float*)d_in[5];
  const float* fw1    = (const float*)d_in[6];
  const float* fb1    = (const float*)d_in[7];
  const float* fw2    = (const float*)d_in[8];
  const float* fb2    = (const float*)d_in[9];
  const float* ln1g   = (const float*)d_in[10];
  const float* ln1b   = (const float*)d_in[11];
  const float* ln2g   = (const float*)d_in[12];
  const float* ln2b   = (const float*)d_in[13];
  const float* mw1    = (const float*)d_in[14];
  const float* mb1    = (const float*)d_in[15];
  const float* mw2    = (const float*)d_in[16];
  const float* mb2    = (const float*)d_in[17];
  float* out = (float*)d_out;

  float* ws = (float*)d_ws;
  float* xbuf  = ws;                   // 384*256
  float* qkv   = xbuf  + 98304;        // 384*768
  float* sc    = qkv   + 294912;       // 4*384*384
  float* attno = sc    + 589824;       // 384*256
  float* proj  = attno + 98304;        // 384*256
  float* ffh   = proj  + 98304;        // 384*1024
  float* U     = ffh   + 393216;       // 384*512
  float* V     = U     + 196608;       // 384*512
  unsigned short* Vbf    = (unsigned short*)(V + 196608);    // 384*512 bf16
  unsigned short* w2frag = (unsigned short*)(V + 294912);    // 64KB
  float* kt    = V + 327680;                                 // 4*64*384

  hipMemcpyAsync(xbuf, node, (size_t)NN * DM * sizeof(float),
                 hipMemcpyDeviceToDevice, stream);
  prep_w2frag<<<dim3(16), 256, 0, stream>>>(mw2, w2frag);
  pair_idx_kernel<<<dim3((NPAIR + 255) / 256), 256, 0, stream>>>(out);

  for (int l = 0; l < 2; ++l) {
    const float* wi  = w_in  + (size_t)l * DM * 768;
    const float* bi  = b_in  + (size_t)l * 768;
    const float* wo  = w_out + (size_t)l * DM * DM;
    const float* bo  = b_out + (size_t)l * DM;
    const float* w1l = fw1   + (size_t)l * DM * FF;
    const float* b1l = fb1   + (size_t)l * FF;
    const float* w2l = fw2   + (size_t)l * FF * DM;
    const float* b2l = fb2   + (size_t)l * DM;

    gemm_tile<<<dim3(12, 6, 1), 256, 0, stream>>>(xbuf, DM, 0, wi, 768, 0, bi,
                                                  qkv, 768, 0, DM, 1.f, 0);
    transpose_k<<<dim3(384), 256, 0, stream>>>(qkv, kt);
    gemm_tile<<<dim3(6, 6, NH), 256, 0, stream>>>(qkv, 768, 64, kt, NN, 64 * NN,
                                                  nullptr, sc, NN, (long)NN * NN,
                                                  64, 0.125f, 0);
    softmax_rows<<<dim3(NH * NN), 128, 0, stream>>>(sc);
    gemm32<<<dim3(2, 12, NH), 256, 0, stream>>>(sc, NN, (long)NN * NN,
                                                qkv + 512, 768, 64, nullptr,
                                                attno, DM, 64, NN, 1.f, 0);
    gemm32<<<dim3(8, 12, 1), 256, 0, stream>>>(attno, DM, 0, wo, DM, 0, bo,
                                               proj, DM, 0, DM, 1.f, 0);
    add_ln<<<dim3(NN), 256, 0, stream>>>(xbuf, proj, ln1g + (size_t)l * DM, ln1b + (size_t)l * DM);
    gemm_tile<<<dim3(16, 6, 1), 256, 0, stream>>>(xbuf, DM, 0, w1l, FF, 0, b1l,
                                                  ffh, FF, 0, DM, 1.f, 1);
    gemm32<<<dim3(8, 12, 1), 256, 0, stream>>>(ffh, FF, 0, w2l, DM, 0, b2l,
                                               proj, DM, 0, FF, 1.f, 0);
    add_ln<<<dim3(NN), 256, 0, stream>>>(xbuf, proj, ln2g + (size_t)l * DM, ln2b + (size_t)l * DM);
  }

  // relation MLP: U = x@W1[0:256]+b1, V = x@W1[256:512], then box/bf16 fixup
  gemm_tile<<<dim3(8, 6, 1), 256, 0, stream>>>(xbuf, DM, 0, mw1, HIDN, 0, mb1,
                                               U, HIDN, 0, DM, 1.f, 0);
  gemm_tile<<<dim3(8, 6, 1), 256, 0, stream>>>(xbuf, DM, 0, mw1 + (size_t)DM * HIDN,
                                               HIDN, 0, nullptr, V, HIDN, 0, DM, 1.f, 0);
  uv_fixup<<<dim3(NN * HIDN / 256), 256, 0, stream>>>(boxes, mw1, U, V, Vbf);
  // pair GEMM: 1 class-tile per wave, fragments resident
  pair_mfma<<<dim3(24, 96), 256, 0, stream>>>(U, Vbf, w2frag, mb2, out);
}

// Round 7
// 369.977 us; speedup vs baseline: 1.0118x; 1.0037x over previous
//
#include <hip/hip_runtime.h>

#define NN 384
#define DM 256
#define NH 4
#define FF 1024
#define HIDN 512
#define NCLS 56
#define NPAIR (NN*(NN-1))   // 147072
#define NI 8

typedef __attribute__((ext_vector_type(8))) short short8v;
typedef __attribute__((ext_vector_type(4))) float f32x4;
typedef __attribute__((ext_vector_type(8))) unsigned short ushort8;
typedef __attribute__((ext_vector_type(4))) unsigned int uint4v;

static __device__ __forceinline__ unsigned short f2bf(float f) {
  unsigned u = __float_as_uint(f);
  unsigned r = u + 0x7fff + ((u >> 16) & 1);   // RNE
  return (unsigned short)(r >> 16);
}
static __device__ __forceinline__ float bf2f(unsigned short v) {
  return __uint_as_float(((unsigned)v) << 16);
}
static __device__ __forceinline__ unsigned cvt_pk_bf16(float lo, float hi) {
  unsigned r;
  asm("v_cvt_pk_bf16_f32 %0, %1, %2" : "=v"(r) : "v"(lo), "v"(hi));
  return r;
}

// ---------------- tiled f32 GEMM 64x64: C = alpha*(A@B) + bias, opt relu ---
__global__ __launch_bounds__(256)
void gemm_tile(const float* __restrict__ A, int lda, long sA,
               const float* __restrict__ B, int ldb, long sB,
               const float* __restrict__ bias,
               float* __restrict__ C, int ldc, long sC,
               int K, float alpha, int relu) {
  __shared__ float As[16][64];
  __shared__ float Bs[16][64];
  A += (size_t)blockIdx.z * sA;
  B += (size_t)blockIdx.z * sB;
  C += (size_t)blockIdx.z * sC;
  int tid = threadIdx.x;
  int tx = tid & 15;
  int ty = tid >> 4;
  int m0 = blockIdx.y * 64;
  int n0 = blockIdx.x * 64;
  int la_r = tid >> 2;
  int la_k = (tid & 3) * 4;
  int lb_k = tid >> 4;
  int lb_n = (tid & 15) * 4;

  float acc[4][4] = {};
  float4 av = *reinterpret_cast<const float4*>(A + (size_t)(m0 + la_r) * lda + la_k);
  float4 bv = *reinterpret_cast<const float4*>(B + (size_t)lb_k * ldb + n0 + lb_n);
  int nchunk = K >> 4;
  for (int ch = 0; ch < nchunk; ++ch) {
    __syncthreads();
    As[la_k + 0][la_r] = av.x;
    As[la_k + 1][la_r] = av.y;
    As[la_k + 2][la_r] = av.z;
    As[la_k + 3][la_r] = av.w;
    *reinterpret_cast<float4*>(&Bs[lb_k][lb_n]) = bv;
    if (ch + 1 < nchunk) {
      int k0 = (ch + 1) << 4;
      av = *reinterpret_cast<const float4*>(A + (size_t)(m0 + la_r) * lda + k0 + la_k);
      bv = *reinterpret_cast<const float4*>(B + (size_t)(k0 + lb_k) * ldb + n0 + lb_n);
    }
    __syncthreads();
    #pragma unroll
    for (int k = 0; k < 16; ++k) {
      float4 a4 = *reinterpret_cast<const float4*>(&As[k][ty * 4]);
      float4 b4 = *reinterpret_cast<const float4*>(&Bs[k][tx * 4]);
      acc[0][0] += a4.x * b4.x; acc[0][1] += a4.x * b4.y; acc[0][2] += a4.x * b4.z; acc[0][3] += a4.x * b4.w;
      acc[1][0] += a4.y * b4.x; acc[1][1] += a4.y * b4.y; acc[1][2] += a4.y * b4.z; acc[1][3] += a4.y * b4.w;
      acc[2][0] += a4.z * b4.x; acc[2][1] += a4.z * b4.y; acc[2][2] += a4.z * b4.z; acc[2][3] += a4.z * b4.w;
      acc[3][0] += a4.w * b4.x; acc[3][1] += a4.w * b4.y; acc[3][2] += a4.w * b4.z; acc[3][3] += a4.w * b4.w;
    }
  }
  float4 bb = make_float4(0.f, 0.f, 0.f, 0.f);
  if (bias) bb = *reinterpret_cast<const float4*>(bias + n0 + tx * 4);
  #pragma unroll
  for (int i = 0; i < 4; ++i) {
    float4 r;
    r.x = acc[i][0] * alpha + bb.x;
    r.y = acc[i][1] * alpha + bb.y;
    r.z = acc[i][2] * alpha + bb.z;
    r.w = acc[i][3] * alpha + bb.w;
    if (relu) {
      r.x = fmaxf(r.x, 0.f); r.y = fmaxf(r.y, 0.f);
      r.z = fmaxf(r.z, 0.f); r.w = fmaxf(r.w, 0.f);
    }
    *reinterpret_cast<float4*>(C + (size_t)(m0 + ty * 4 + i) * ldc + n0 + tx * 4) = r;
  }
}

// ---------------- tiled f32 GEMM 32x32 (more blocks for small outputs) ----
__global__ __launch_bounds__(256)
void gemm32(const float* __restrict__ A, int lda, long sA,
            const float* __restrict__ B, int ldb, long sB,
            const float* __restrict__ bias,
            float* __restrict__ C, int ldc, long sC,
            int K, float alpha, int relu) {
  __shared__ float As[16][33];
  __shared__ float Bs[16][33];
  A += (size_t)blockIdx.z * sA;
  B += (size_t)blockIdx.z * sB;
  C += (size_t)blockIdx.z * sC;
  int tid = threadIdx.x;
  int tx = tid & 15;
  int ty = tid >> 4;
  int m0 = blockIdx.y * 32;
  int n0 = blockIdx.x * 32;
  float acc[2][2] = {};
  int ar = (tid & 127) >> 2;
  int ak = (tid & 3) * 4;
  int bk = (tid & 127) >> 3;
  int bn = ((tid & 127) & 7) * 4;
  bool doA = tid < 128;
  float4 pre;
  if (doA) pre = *reinterpret_cast<const float4*>(A + (size_t)(m0 + ar) * lda + ak);
  else     pre = *reinterpret_cast<const float4*>(B + (size_t)bk * ldb + n0 + bn);
  int nchunk = K >> 4;
  for (int ch = 0; ch < nchunk; ++ch) {
    __syncthreads();
    if (doA) {
      As[ak + 0][ar] = pre.x; As[ak + 1][ar] = pre.y;
      As[ak + 2][ar] = pre.z; As[ak + 3][ar] = pre.w;
    } else {
      Bs[bk][bn + 0] = pre.x; Bs[bk][bn + 1] = pre.y;
      Bs[bk][bn + 2] = pre.z; Bs[bk][bn + 3] = pre.w;
    }
    if (ch + 1 < nchunk) {
      int k0 = (ch + 1) << 4;
      if (doA) pre = *reinterpret_cast<const float4*>(A + (size_t)(m0 + ar) * lda + k0 + ak);
      else     pre = *reinterpret_cast<const float4*>(B + (size_t)(k0 + bk) * ldb + n0 + bn);
    }
    __syncthreads();
    #pragma unroll
    for (int k = 0; k < 16; ++k) {
      float a0 = As[k][ty * 2], a1 = As[k][ty * 2 + 1];
      float b0 = Bs[k][tx * 2], b1 = Bs[k][tx * 2 + 1];
      acc[0][0] += a0 * b0; acc[0][1] += a0 * b1;
      acc[1][0] += a1 * b0; acc[1][1] += a1 * b1;
    }
  }
  float bb0 = 0.f, bb1 = 0.f;
  if (bias) { bb0 = bias[n0 + tx * 2]; bb1 = bias[n0 + tx * 2 + 1]; }
  #pragma unroll
  for (int r = 0; r < 2; ++r) {
    float v0 = acc[r][0] * alpha + bb0;
    float v1 = acc[r][1] * alpha + bb1;
    if (relu) { v0 = fmaxf(v0, 0.f); v1 = fmaxf(v1, 0.f); }
    float2 st = make_float2(v0, v1);
    *reinterpret_cast<float2*>(C + (size_t)(m0 + ty * 2 + r) * ldc + n0 + tx * 2) = st;
  }
}

// ---------------- transpose K heads ---------------------------------------
__global__ __launch_bounds__(256)
void transpose_k(const float* __restrict__ qkv, float* __restrict__ kt) {
  int idx = blockIdx.x * 256 + threadIdx.x;
  int m = idx % NN;
  int d = (idx / NN) & 63;
  int h = idx / (NN * 64);
  kt[idx] = qkv[(size_t)m * 768 + 256 + h * 64 + d];
}

// ---------------- row softmax over 384 ------------------------------------
__global__ __launch_bounds__(128)
void softmax_rows(float* __restrict__ sc) {
  float* row = sc + (size_t)blockIdx.x * NN;
  int t = threadIdx.x;
  float v0 = row[t], v1 = row[t + 128], v2 = row[t + 256];
  __shared__ float red[128];
  float m = fmaxf(v0, fmaxf(v1, v2));
  red[t] = m; __syncthreads();
  for (int s = 64; s > 0; s >>= 1) { if (t < s) red[t] = fmaxf(red[t], red[t + s]); __syncthreads(); }
  m = red[0]; __syncthreads();
  float e0 = expf(v0 - m), e1 = expf(v1 - m), e2 = expf(v2 - m);
  red[t] = e0 + e1 + e2; __syncthreads();
  for (int s = 64; s > 0; s >>= 1) { if (t < s) red[t] += red[t + s]; __syncthreads(); }
  float inv = 1.0f / red[0];
  row[t] = e0 * inv; row[t + 128] = e1 * inv; row[t + 256] = e2 * inv;
}

// ---------------- residual add + LayerNorm --------------------------------
__global__ __launch_bounds__(256)
void add_ln(float* __restrict__ x, const float* __restrict__ r,
            const float* __restrict__ g, const float* __restrict__ b) {
  int i = blockIdx.x, t = threadIdx.x;
  float v = x[(size_t)i * DM + t] + r[(size_t)i * DM + t];
  __shared__ float red[256];
  red[t] = v; __syncthreads();
  for (int s = 128; s > 0; s >>= 1) { if (t < s) red[t] += red[t + s]; __syncthreads(); }
  float mu = red[0] * (1.0f / DM); __syncthreads();
  float dv = v - mu;
  red[t] = dv * dv; __syncthreads();
  for (int s = 128; s > 0; s >>= 1) { if (t < s) red[t] += red[t + s]; __syncthreads(); }
  float var = red[0] * (1.0f / DM);
  float inv = rsqrtf(var + 1e-5f);
  x[(size_t)i * DM + t] = dv * inv * g[t] + b[t];
}

// ------ add box terms; U stays f32, V goes to global bf16 -----------------
__global__ __launch_bounds__(256)
void uv_fixup(const float* __restrict__ boxes, const float* __restrict__ w1,
              float* __restrict__ U, const float* __restrict__ V,
              unsigned short* __restrict__ Vbf) {
  int idx = blockIdx.x * 256 + threadIdx.x;   // NN*HIDN
  int i = idx >> 9, k = idx & 511;
  float u = U[idx], v = V[idx];
  #pragma unroll
  for (int c = 0; c < 4; ++c) {
    float bv = boxes[i * 4 + c];
    u += bv * w1[(size_t)(512 + c) * HIDN + k];
    v += bv * w1[(size_t)(516 + c) * HIDN + k];
  }
  U[idx] = u;
  Vbf[idx] = f2bf(v);
}

// ---------------- pack W2 into MFMA B-fragment order (bf16) ---------------
// lane l holds B[k = ks*32 + (l>>4)*8 + r][n = nt*16 + (l&15)]
__global__ __launch_bounds__(256)
void prep_w2frag(const float* __restrict__ w2, unsigned short* __restrict__ frag) {
  int idx = blockIdx.x * 256 + threadIdx.x;   // 16*4*64 = 4096
  int l = idx & 63;
  int nt = (idx >> 6) & 3;
  int ks = idx >> 8;
  int kb = ks * 32 + ((l >> 4) * 8);
  int n = nt * 16 + (l & 15);
  #pragma unroll
  for (int r = 0; r < 8; ++r) {
    float v = (n < NCLS) ? w2[(size_t)(kb + r) * NCLS + n] : 0.f;
    frag[(size_t)idx * 8 + r] = f2bf(v);
  }
}

// ---------------- pair indices output -------------------------------------
__global__ __launch_bounds__(256)
void pair_idx_kernel(float* __restrict__ out) {
  int p = blockIdx.x * 256 + threadIdx.x;
  if (p >= NPAIR) return;
  int i = p / (NN - 1);
  int r = p - i * (NN - 1);
  int j = r + (r >= i ? 1 : 0);
  out[2 * p + 0] = (float)i;
  out[2 * p + 1] = (float)j;
}

// ---------------- pair MLP via MFMA v5: asm-pinned resident fragments -----
// Wave task: (jt of 16 j's, class-tile nth, NI i's). bfrag (64 VGPR) and
// vfrag (64 VGPR) are loaded once then PINNED via asm "+v" so the register
// allocator cannot re-load them inside the i-loop (r5/r6 failure mode:
// VGPR_Count 112-144 proved the compiler reloaded from L2 every iteration,
// serializing ~350-cycle round-trips). Inner loop per i: 32 batched
// L1-broadcast U loads + build (add/max/cvt_pk) + 16 MFMA + 4 stores.
__global__ __launch_bounds__(256, 2)
void pair_mfma(const float* __restrict__ U, const unsigned short* __restrict__ Vbf,
               const unsigned short* __restrict__ w2frag,
               const float* __restrict__ b2, float* __restrict__ out) {
  int tid = threadIdx.x;
  int nth = tid >> 6;                        // class-tile 0..3 (one per wave)
  int lane = tid & 63;
  int jt = blockIdx.x;                       // 0..23
  int i0 = blockIdx.y * NI;                  // 48 i-groups

  // B fragments for this wave's class-tile: 16 ks x 4 VGPR = 64 VGPR
  short8v bfrag[16];
  #pragma unroll
  for (int ks = 0; ks < 16; ++ks)
    bfrag[ks] = *reinterpret_cast<const short8v*>(
        w2frag + ((size_t)(ks * 4 + nth) * 64 + lane) * 8);

  int colc = lane & 15;
  int g = lane >> 4;
  int cls = nth * 16 + colc;
  bool cls_ok = (cls < NCLS);
  float b2v = cls_ok ? b2[cls] : 0.f;

  // V fragments: this lane's A-row, all 16 k-slices: 64 VGPR
  int j_row = jt * 16 + colc;
  ushort8 vfrag[16];
  #pragma unroll
  for (int ks = 0; ks < 16; ++ks)
    vfrag[ks] = *reinterpret_cast<const ushort8*>(
        Vbf + (size_t)j_row * HIDN + ks * 32 + g * 8);

  // PIN: make fragment values opaque -> cannot be rematerialized by reload.
  #pragma unroll
  for (int ks = 0; ks < 16; ++ks) {
    asm volatile("" : "+v"(bfrag[ks]));
    asm volatile("" : "+v"(vfrag[ks]));
  }

  float* lg = out + 2 * (size_t)NPAIR;

  for (int ii = 0; ii < NI; ++ii) {
    int i = i0 + ii;
    const float* urow = U + (size_t)i * HIDN + g * 8;
    f32x4 acc = {};
    #pragma unroll
    for (int ks = 0; ks < 16; ++ks) {
      float4 ua = *reinterpret_cast<const float4*>(urow + ks * 32);
      float4 ub = *reinterpret_cast<const float4*>(urow + ks * 32 + 4);
      ushort8 v8 = vfrag[ks];
      float h0 = fmaxf(bf2f(v8[0]) + ua.x, 0.f);
      float h1 = fmaxf(bf2f(v8[1]) + ua.y, 0.f);
      float h2 = fmaxf(bf2f(v8[2]) + ua.z, 0.f);
      float h3 = fmaxf(bf2f(v8[3]) + ua.w, 0.f);
      float h4 = fmaxf(bf2f(v8[4]) + ub.x, 0.f);
      float h5 = fmaxf(bf2f(v8[5]) + ub.y, 0.f);
      float h6 = fmaxf(bf2f(v8[6]) + ub.z, 0.f);
      float h7 = fmaxf(bf2f(v8[7]) + ub.w, 0.f);
      uint4v pk;
      pk[0] = cvt_pk_bf16(h0, h1);
      pk[1] = cvt_pk_bf16(h2, h3);
      pk[2] = cvt_pk_bf16(h4, h5);
      pk[3] = cvt_pk_bf16(h6, h7);
      short8v a = *reinterpret_cast<short8v*>(&pk);
      acc = __builtin_amdgcn_mfma_f32_16x16x32_bf16(a, bfrag[ks], acc, 0, 0, 0);
    }
    if (cls_ok) {
      #pragma unroll
      for (int r = 0; r < 4; ++r) {
        int j = jt * 16 + g * 4 + r;
        if (j == i) continue;
        int p = i * (NN - 1) + (j > i ? j - 1 : j);
        lg[(size_t)p * NCLS + cls] = acc[r] + b2v;
      }
    }
  }
}

// --------------------------------------------------------------------------
extern "C" void kernel_launch(void* const* d_in, const int* in_sizes, int n_in,
                              void* d_out, int out_size, void* d_ws, size_t ws_size,
                              hipStream_t stream) {
  const float* node   = (const float*)d_in[0];
  const float* boxes  = (const float*)d_in[1];
  const float* w_in   = (const float*)d_in[2];
  const float* b_in   = (const float*)d_in[3];
  const float* w_out  = (const float*)d_in[4];
  const float* b_out  = (const float*)d_in[5];
  const float* fw1    = (const float*)d_in[6];
  const float* fb1    = (const float*)d_in[7];
  const float* fw2    = (const float*)d_in[8];
  const float* fb2    = (const float*)d_in[9];
  const float* ln1g   = (const float*)d_in[10];
  const float* ln1b   = (const float*)d_in[11];
  const float* ln2g   = (const float*)d_in[12];
  const float* ln2b   = (const float*)d_in[13];
  const float* mw1    = (const float*)d_in[14];
  const float* mb1    = (const float*)d_in[15];
  const float* mw2    = (const float*)d_in[16];
  const float* mb2    = (const float*)d_in[17];
  float* out = (float*)d_out;

  float* ws = (float*)d_ws;
  float* xbuf  = ws;                   // 384*256
  float* qkv   = xbuf  + 98304;        // 384*768
  float* sc    = qkv   + 294912;       // 4*384*384
  float* attno = sc    + 589824;       // 384*256
  float* proj  = attno + 98304;        // 384*256
  float* ffh   = proj  + 98304;        // 384*1024
  float* U     = ffh   + 393216;       // 384*512
  float* V     = U     + 196608;       // 384*512
  unsigned short* Vbf    = (unsigned short*)(V + 196608);    // 384*512 bf16
  unsigned short* w2frag = (unsigned short*)(V + 294912);    // 64KB
  float* kt    = V + 327680;                                 // 4*64*384

  hipMemcpyAsync(xbuf, node, (size_t)NN * DM * sizeof(float),
                 hipMemcpyDeviceToDevice, stream);
  prep_w2frag<<<dim3(16), 256, 0, stream>>>(mw2, w2frag);
  pair_idx_kernel<<<dim3((NPAIR + 255) / 256), 256, 0, stream>>>(out);

  for (int l = 0; l < 2; ++l) {
    const float* wi  = w_in  + (size_t)l * DM * 768;
    const float* bi  = b_in  + (size_t)l * 768;
    const float* wo  = w_out + (size_t)l * DM * DM;
    const float* bo  = b_out + (size_t)l * DM;
    const float* w1l = fw1   + (size_t)l * DM * FF;
    const float* b1l = fb1   + (size_t)l * FF;
    const float* w2l = fw2   + (size_t)l * FF * DM;
    const float* b2l = fb2   + (size_t)l * DM;

    gemm_tile<<<dim3(12, 6, 1), 256, 0, stream>>>(xbuf, DM, 0, wi, 768, 0, bi,
                                                  qkv, 768, 0, DM, 1.f, 0);
    transpose_k<<<dim3(384), 256, 0, stream>>>(qkv, kt);
    gemm_tile<<<dim3(6, 6, NH), 256, 0, stream>>>(qkv, 768, 64, kt, NN, 64 * NN,
                                                  nullptr, sc, NN, (long)NN * NN,
                                                  64, 0.125f, 0);
    softmax_rows<<<dim3(NH * NN), 128, 0, stream>>>(sc);
    gemm32<<<dim3(2, 12, NH), 256, 0, stream>>>(sc, NN, (long)NN * NN,
                                                qkv + 512, 768, 64, nullptr,
                                                attno, DM, 64, NN, 1.f, 0);
    gemm32<<<dim3(8, 12, 1), 256, 0, stream>>>(attno, DM, 0, wo, DM, 0, bo,
                                               proj, DM, 0, DM, 1.f, 0);
    add_ln<<<dim3(NN), 256, 0, stream>>>(xbuf, proj, ln1g + (size_t)l * DM, ln1b + (size_t)l * DM);
    gemm_tile<<<dim3(16, 6, 1), 256, 0, stream>>>(xbuf, DM, 0, w1l, FF, 0, b1l,
                                                  ffh, FF, 0, DM, 1.f, 1);
    gemm32<<<dim3(8, 12, 1), 256, 0, stream>>>(ffh, FF, 0, w2l, DM, 0, b2l,
                                               proj, DM, 0, FF, 1.f, 0);
    add_ln<<<dim3(NN), 256, 0, stream>>>(xbuf, proj, ln2g + (size_t)l * DM, ln2b + (size_t)l * DM);
  }

  // relation MLP: U = x@W1[0:256]+b1, V = x@W1[256:512], then box/bf16 fixup
  gemm_tile<<<dim3(8, 6, 1), 256, 0, stream>>>(xbuf, DM, 0, mw1, HIDN, 0, mb1,
                                               U, HIDN, 0, DM, 1.f, 0);
  gemm_tile<<<dim3(8, 6, 1), 256, 0, stream>>>(xbuf, DM, 0, mw1 + (size_t)DM * HIDN,
                                               HIDN, 0, nullptr, V, HIDN, 0, DM, 1.f, 0);
  uv_fixup<<<dim3(NN * HIDN / 256), 256, 0, stream>>>(boxes, mw1, U, V, Vbf);
  // pair GEMM: fragments pinned resident via asm
  pair_mfma<<<dim3(24, NN / NI), 256, 0, stream>>>(U, Vbf, w2frag, mb2, out);
}

// Round 8
// 355.662 us; speedup vs baseline: 1.0525x; 1.0402x over previous
//
#include <hip/hip_runtime.h>

#define NN 384
#define DM 256
#define NH 4
#define FF 1024
#define HIDN 512
#define NCLS 56
#define NPAIR (NN*(NN-1))   // 147072

typedef __attribute__((ext_vector_type(8))) short short8v;
typedef __attribute__((ext_vector_type(4))) float f32x4;
typedef __attribute__((ext_vector_type(8))) unsigned short ushort8;
typedef __attribute__((ext_vector_type(4))) unsigned int uint4v;

static __device__ __forceinline__ unsigned short f2bf(float f) {
  unsigned u = __float_as_uint(f);
  unsigned r = u + 0x7fff + ((u >> 16) & 1);   // RNE
  return (unsigned short)(r >> 16);
}
static __device__ __forceinline__ float bf2f(unsigned short v) {
  return __uint_as_float(((unsigned)v) << 16);
}
static __device__ __forceinline__ unsigned cvt_pk_bf16(float lo, float hi) {
  unsigned r;
  asm("v_cvt_pk_bf16_f32 %0, %1, %2" : "=v"(r) : "v"(lo), "v"(hi));
  return r;
}

// ---------------- tiled f32 GEMM 64x64: C = alpha*(A@B) + bias, opt relu ---
__global__ __launch_bounds__(256)
void gemm_tile(const float* __restrict__ A, int lda, long sA,
               const float* __restrict__ B, int ldb, long sB,
               const float* __restrict__ bias,
               float* __restrict__ C, int ldc, long sC,
               int K, float alpha, int relu) {
  __shared__ float As[16][64];
  __shared__ float Bs[16][64];
  A += (size_t)blockIdx.z * sA;
  B += (size_t)blockIdx.z * sB;
  C += (size_t)blockIdx.z * sC;
  int tid = threadIdx.x;
  int tx = tid & 15;
  int ty = tid >> 4;
  int m0 = blockIdx.y * 64;
  int n0 = blockIdx.x * 64;
  int la_r = tid >> 2;
  int la_k = (tid & 3) * 4;
  int lb_k = tid >> 4;
  int lb_n = (tid & 15) * 4;

  float acc[4][4] = {};
  float4 av = *reinterpret_cast<const float4*>(A + (size_t)(m0 + la_r) * lda + la_k);
  float4 bv = *reinterpret_cast<const float4*>(B + (size_t)lb_k * ldb + n0 + lb_n);
  int nchunk = K >> 4;
  for (int ch = 0; ch < nchunk; ++ch) {
    __syncthreads();
    As[la_k + 0][la_r] = av.x;
    As[la_k + 1][la_r] = av.y;
    As[la_k + 2][la_r] = av.z;
    As[la_k + 3][la_r] = av.w;
    *reinterpret_cast<float4*>(&Bs[lb_k][lb_n]) = bv;
    if (ch + 1 < nchunk) {
      int k0 = (ch + 1) << 4;
      av = *reinterpret_cast<const float4*>(A + (size_t)(m0 + la_r) * lda + k0 + la_k);
      bv = *reinterpret_cast<const float4*>(B + (size_t)(k0 + lb_k) * ldb + n0 + lb_n);
    }
    __syncthreads();
    #pragma unroll
    for (int k = 0; k < 16; ++k) {
      float4 a4 = *reinterpret_cast<const float4*>(&As[k][ty * 4]);
      float4 b4 = *reinterpret_cast<const float4*>(&Bs[k][tx * 4]);
      acc[0][0] += a4.x * b4.x; acc[0][1] += a4.x * b4.y; acc[0][2] += a4.x * b4.z; acc[0][3] += a4.x * b4.w;
      acc[1][0] += a4.y * b4.x; acc[1][1] += a4.y * b4.y; acc[1][2] += a4.y * b4.z; acc[1][3] += a4.y * b4.w;
      acc[2][0] += a4.z * b4.x; acc[2][1] += a4.z * b4.y; acc[2][2] += a4.z * b4.z; acc[2][3] += a4.z * b4.w;
      acc[3][0] += a4.w * b4.x; acc[3][1] += a4.w * b4.y; acc[3][2] += a4.w * b4.z; acc[3][3] += a4.w * b4.w;
    }
  }
  float4 bb = make_float4(0.f, 0.f, 0.f, 0.f);
  if (bias) bb = *reinterpret_cast<const float4*>(bias + n0 + tx * 4);
  #pragma unroll
  for (int i = 0; i < 4; ++i) {
    float4 r;
    r.x = acc[i][0] * alpha + bb.x;
    r.y = acc[i][1] * alpha + bb.y;
    r.z = acc[i][2] * alpha + bb.z;
    r.w = acc[i][3] * alpha + bb.w;
    if (relu) {
      r.x = fmaxf(r.x, 0.f); r.y = fmaxf(r.y, 0.f);
      r.z = fmaxf(r.z, 0.f); r.w = fmaxf(r.w, 0.f);
    }
    *reinterpret_cast<float4*>(C + (size_t)(m0 + ty * 4 + i) * ldc + n0 + tx * 4) = r;
  }
}

// ---------------- tiled f32 GEMM 32x32 (more blocks for small outputs) ----
__global__ __launch_bounds__(256)
void gemm32(const float* __restrict__ A, int lda, long sA,
            const float* __restrict__ B, int ldb, long sB,
            const float* __restrict__ bias,
            float* __restrict__ C, int ldc, long sC,
            int K, float alpha, int relu) {
  __shared__ float As[16][33];
  __shared__ float Bs[16][33];
  A += (size_t)blockIdx.z * sA;
  B += (size_t)blockIdx.z * sB;
  C += (size_t)blockIdx.z * sC;
  int tid = threadIdx.x;
  int tx = tid & 15;
  int ty = tid >> 4;
  int m0 = blockIdx.y * 32;
  int n0 = blockIdx.x * 32;
  float acc[2][2] = {};
  int ar = (tid & 127) >> 2;
  int ak = (tid & 3) * 4;
  int bk = (tid & 127) >> 3;
  int bn = ((tid & 127) & 7) * 4;
  bool doA = tid < 128;
  float4 pre;
  if (doA) pre = *reinterpret_cast<const float4*>(A + (size_t)(m0 + ar) * lda + ak);
  else     pre = *reinterpret_cast<const float4*>(B + (size_t)bk * ldb + n0 + bn);
  int nchunk = K >> 4;
  for (int ch = 0; ch < nchunk; ++ch) {
    __syncthreads();
    if (doA) {
      As[ak + 0][ar] = pre.x; As[ak + 1][ar] = pre.y;
      As[ak + 2][ar] = pre.z; As[ak + 3][ar] = pre.w;
    } else {
      Bs[bk][bn + 0] = pre.x; Bs[bk][bn + 1] = pre.y;
      Bs[bk][bn + 2] = pre.z; Bs[bk][bn + 3] = pre.w;
    }
    if (ch + 1 < nchunk) {
      int k0 = (ch + 1) << 4;
      if (doA) pre = *reinterpret_cast<const float4*>(A + (size_t)(m0 + ar) * lda + k0 + ak);
      else     pre = *reinterpret_cast<const float4*>(B + (size_t)(k0 + bk) * ldb + n0 + bn);
    }
    __syncthreads();
    #pragma unroll
    for (int k = 0; k < 16; ++k) {
      float a0 = As[k][ty * 2], a1 = As[k][ty * 2 + 1];
      float b0 = Bs[k][tx * 2], b1 = Bs[k][tx * 2 + 1];
      acc[0][0] += a0 * b0; acc[0][1] += a0 * b1;
      acc[1][0] += a1 * b0; acc[1][1] += a1 * b1;
    }
  }
  float bb0 = 0.f, bb1 = 0.f;
  if (bias) { bb0 = bias[n0 + tx * 2]; bb1 = bias[n0 + tx * 2 + 1]; }
  #pragma unroll
  for (int r = 0; r < 2; ++r) {
    float v0 = acc[r][0] * alpha + bb0;
    float v1 = acc[r][1] * alpha + bb1;
    if (relu) { v0 = fmaxf(v0, 0.f); v1 = fmaxf(v1, 0.f); }
    float2 st = make_float2(v0, v1);
    *reinterpret_cast<float2*>(C + (size_t)(m0 + ty * 2 + r) * ldc + n0 + tx * 2) = st;
  }
}

// ---------------- transpose K heads ---------------------------------------
__global__ __launch_bounds__(256)
void transpose_k(const float* __restrict__ qkv, float* __restrict__ kt) {
  int idx = blockIdx.x * 256 + threadIdx.x;
  int m = idx % NN;
  int d = (idx / NN) & 63;
  int h = idx / (NN * 64);
  kt[idx] = qkv[(size_t)m * 768 + 256 + h * 64 + d];
}

// ---------------- row softmax over 384 ------------------------------------
__global__ __launch_bounds__(128)
void softmax_rows(float* __restrict__ sc) {
  float* row = sc + (size_t)blockIdx.x * NN;
  int t = threadIdx.x;
  float v0 = row[t], v1 = row[t + 128], v2 = row[t + 256];
  __shared__ float red[128];
  float m = fmaxf(v0, fmaxf(v1, v2));
  red[t] = m; __syncthreads();
  for (int s = 64; s > 0; s >>= 1) { if (t < s) red[t] = fmaxf(red[t], red[t + s]); __syncthreads(); }
  m = red[0]; __syncthreads();
  float e0 = expf(v0 - m), e1 = expf(v1 - m), e2 = expf(v2 - m);
  red[t] = e0 + e1 + e2; __syncthreads();
  for (int s = 64; s > 0; s >>= 1) { if (t < s) red[t] += red[t + s]; __syncthreads(); }
  float inv = 1.0f / red[0];
  row[t] = e0 * inv; row[t + 128] = e1 * inv; row[t + 256] = e2 * inv;
}

// ---------------- residual add + LayerNorm --------------------------------
__global__ __launch_bounds__(256)
void add_ln(float* __restrict__ x, const float* __restrict__ r,
            const float* __restrict__ g, const float* __restrict__ b) {
  int i = blockIdx.x, t = threadIdx.x;
  float v = x[(size_t)i * DM + t] + r[(size_t)i * DM + t];
  __shared__ float red[256];
  red[t] = v; __syncthreads();
  for (int s = 128; s > 0; s >>= 1) { if (t < s) red[t] += red[t + s]; __syncthreads(); }
  float mu = red[0] * (1.0f / DM); __syncthreads();
  float dv = v - mu;
  red[t] = dv * dv; __syncthreads();
  for (int s = 128; s > 0; s >>= 1) { if (t < s) red[t] += red[t + s]; __syncthreads(); }
  float var = red[0] * (1.0f / DM);
  float inv = rsqrtf(var + 1e-5f);
  x[(size_t)i * DM + t] = dv * inv * g[t] + b[t];
}

// ------ add box terms + b1; U stays f32, V goes to global bf16 ------------
__global__ __launch_bounds__(256)
void uv_fixup(const float* __restrict__ boxes, const float* __restrict__ w1,
              const float* __restrict__ b1,
              float* __restrict__ U, const float* __restrict__ V,
              unsigned short* __restrict__ Vbf) {
  int idx = blockIdx.x * 256 + threadIdx.x;   // NN*HIDN
  int i = idx >> 9, k = idx & 511;
  float u = U[idx] + b1[k], v = V[idx];
  #pragma unroll
  for (int c = 0; c < 4; ++c) {
    float bv = boxes[i * 4 + c];
    u += bv * w1[(size_t)(512 + c) * HIDN + k];
    v += bv * w1[(size_t)(516 + c) * HIDN + k];
  }
  U[idx] = u;
  Vbf[idx] = f2bf(v);
}

// ---------------- pack W2 into MFMA B-fragment order (bf16) ---------------
// lane l holds B[k = ks*32 + (l>>4)*8 + r][n = nt*16 + (l&15)]
__global__ __launch_bounds__(256)
void prep_w2frag(const float* __restrict__ w2, unsigned short* __restrict__ frag) {
  int idx = blockIdx.x * 256 + threadIdx.x;   // 16*4*64 = 4096
  int l = idx & 63;
  int nt = (idx >> 6) & 3;
  int ks = idx >> 8;
  int kb = ks * 32 + ((l >> 4) * 8);
  int n = nt * 16 + (l & 15);
  #pragma unroll
  for (int r = 0; r < 8; ++r) {
    float v = (n < NCLS) ? w2[(size_t)(kb + r) * NCLS + n] : 0.f;
    frag[(size_t)idx * 8 + r] = f2bf(v);
  }
}

// ---------------- pair indices output -------------------------------------
__global__ __launch_bounds__(256)
void pair_idx_kernel(float* __restrict__ out) {
  int p = blockIdx.x * 256 + threadIdx.x;
  if (p >= NPAIR) return;
  int i = p / (NN - 1);
  int r = p - i * (NN - 1);
  int j = r + (r >= i ? 1 : 0);
  out[2 * p + 0] = (float)i;
  out[2 * p + 1] = (float)j;
}

// ---------------- pair MLP via MFMA v6: straight-line wave tasks ----------
// r5-r7 lesson: ANY i-loop makes the allocator reload/spill loop-invariant
// fragments (VGPR stuck at 112, occupancy ~16%, 127us). v6: one wave = one
// (i, 16-j tile, class-tile) task, zero loops. ~48 independent 16B loads ->
// build -> 16 MFMA -> 4 stores. w2frag (64KB) and Vbf (384KB) are L2-hot.
// 8 waves/block: 4 class-tiles x 2 i's (amortizes V via L1 across nt-waves).
__global__ __launch_bounds__(512)
void pair_mfma(const float* __restrict__ U, const unsigned short* __restrict__ Vbf,
               const unsigned short* __restrict__ w2frag,
               const float* __restrict__ b2, float* __restrict__ out) {
  int tid = threadIdx.x;
  int wave = tid >> 6;                 // 0..7
  int lane = tid & 63;
  int nth = wave & 3;                  // class-tile
  int ih = wave >> 2;                  // i within block pair
  int jt = blockIdx.x;                 // 0..23
  int i = blockIdx.y * 2 + ih;         // 0..383

  int colc = lane & 15;
  int g = lane >> 4;
  int cls = nth * 16 + colc;
  bool cls_ok = (cls < NCLS);
  float b2v = cls_ok ? b2[cls] : 0.f;
  int j_row = jt * 16 + colc;

  const unsigned short* bsrc = w2frag + ((size_t)nth * 64 + lane) * 8;
  const unsigned short* vsrc = Vbf + (size_t)j_row * HIDN + g * 8;
  const float* urow = U + (size_t)i * HIDN + g * 8;

  f32x4 acc = {};
  #pragma unroll
  for (int ks = 0; ks < 16; ++ks) {
    short8v b = *reinterpret_cast<const short8v*>(bsrc + (size_t)ks * 4 * 64 * 8);
    ushort8 v8 = *reinterpret_cast<const ushort8*>(vsrc + ks * 32);
    float4 ua = *reinterpret_cast<const float4*>(urow + ks * 32);
    float4 ub = *reinterpret_cast<const float4*>(urow + ks * 32 + 4);
    float h0 = fmaxf(bf2f(v8[0]) + ua.x, 0.f);
    float h1 = fmaxf(bf2f(v8[1]) + ua.y, 0.f);
    float h2 = fmaxf(bf2f(v8[2]) + ua.z, 0.f);
    float h3 = fmaxf(bf2f(v8[3]) + ua.w, 0.f);
    float h4 = fmaxf(bf2f(v8[4]) + ub.x, 0.f);
    float h5 = fmaxf(bf2f(v8[5]) + ub.y, 0.f);
    float h6 = fmaxf(bf2f(v8[6]) + ub.z, 0.f);
    float h7 = fmaxf(bf2f(v8[7]) + ub.w, 0.f);
    uint4v pk;
    pk[0] = cvt_pk_bf16(h0, h1);
    pk[1] = cvt_pk_bf16(h2, h3);
    pk[2] = cvt_pk_bf16(h4, h5);
    pk[3] = cvt_pk_bf16(h6, h7);
    short8v a = *reinterpret_cast<short8v*>(&pk);
    acc = __builtin_amdgcn_mfma_f32_16x16x32_bf16(a, b, acc, 0, 0, 0);
  }

  if (cls_ok) {
    float* lg = out + 2 * (size_t)NPAIR;
    #pragma unroll
    for (int r = 0; r < 4; ++r) {
      int j = jt * 16 + g * 4 + r;
      if (j == i) continue;
      int p = i * (NN - 1) + (j > i ? j - 1 : j);
      lg[(size_t)p * NCLS + cls] = acc[r] + b2v;
    }
  }
}

// --------------------------------------------------------------------------
extern "C" void kernel_launch(void* const* d_in, const int* in_sizes, int n_in,
                              void* d_out, int out_size, void* d_ws, size_t ws_size,
                              hipStream_t stream) {
  const float* node   = (const float*)d_in[0];
  const float* boxes  = (const float*)d_in[1];
  const float* w_in   = (const float*)d_in[2];
  const float* b_in   = (const float*)d_in[3];
  const float* w_out  = (const float*)d_in[4];
  const float* b_out  = (const float*)d_in[5];
  const float* fw1    = (const float*)d_in[6];
  const float* fb1    = (const float*)d_in[7];
  const float* fw2    = (const float*)d_in[8];
  const float* fb2    = (const float*)d_in[9];
  const float* ln1g   = (const float*)d_in[10];
  const float* ln1b   = (const float*)d_in[11];
  const float* ln2g   = (const float*)d_in[12];
  const float* ln2b   = (const float*)d_in[13];
  const float* mw1    = (const float*)d_in[14];
  const float* mb1    = (const float*)d_in[15];
  const float* mw2    = (const float*)d_in[16];
  const float* mb2    = (const float*)d_in[17];
  float* out = (float*)d_out;

  float* ws = (float*)d_ws;
  float* xbuf  = ws;                   // 384*256
  float* qkv   = xbuf  + 98304;        // 384*768
  float* sc    = qkv   + 294912;       // 4*384*384
  float* attno = sc    + 589824;       // 384*256
  float* proj  = attno + 98304;        // 384*256
  float* ffh   = proj  + 98304;        // 384*1024
  float* U     = ffh   + 393216;       // 384*512
  float* V     = U     + 196608;       // 384*512  (must follow U contiguously)
  unsigned short* Vbf    = (unsigned short*)(V + 196608);    // 384*512 bf16
  unsigned short* w2frag = (unsigned short*)(V + 294912);    // 64KB
  float* kt    = V + 327680;                                 // 4*64*384

  hipMemcpyAsync(xbuf, node, (size_t)NN * DM * sizeof(float),
                 hipMemcpyDeviceToDevice, stream);
  prep_w2frag<<<dim3(16), 256, 0, stream>>>(mw2, w2frag);
  pair_idx_kernel<<<dim3((NPAIR + 255) / 256), 256, 0, stream>>>(out);

  for (int l = 0; l < 2; ++l) {
    const float* wi  = w_in  + (size_t)l * DM * 768;
    const float* bi  = b_in  + (size_t)l * 768;
    const float* wo  = w_out + (size_t)l * DM * DM;
    const float* bo  = b_out + (size_t)l * DM;
    const float* w1l = fw1   + (size_t)l * DM * FF;
    const float* b1l = fb1   + (size_t)l * FF;
    const float* w2l = fw2   + (size_t)l * FF * DM;
    const float* b2l = fb2   + (size_t)l * DM;

    gemm_tile<<<dim3(12, 6, 1), 256, 0, stream>>>(xbuf, DM, 0, wi, 768, 0, bi,
                                                  qkv, 768, 0, DM, 1.f, 0);
    transpose_k<<<dim3(384), 256, 0, stream>>>(qkv, kt);
    gemm_tile<<<dim3(6, 6, NH), 256, 0, stream>>>(qkv, 768, 64, kt, NN, 64 * NN,
                                                  nullptr, sc, NN, (long)NN * NN,
                                                  64, 0.125f, 0);
    softmax_rows<<<dim3(NH * NN), 128, 0, stream>>>(sc);
    gemm32<<<dim3(2, 12, NH), 256, 0, stream>>>(sc, NN, (long)NN * NN,
                                                qkv + 512, 768, 64, nullptr,
                                                attno, DM, 64, NN, 1.f, 0);
    gemm32<<<dim3(8, 12, 1), 256, 0, stream>>>(attno, DM, 0, wo, DM, 0, bo,
                                               proj, DM, 0, DM, 1.f, 0);
    add_ln<<<dim3(NN), 256, 0, stream>>>(xbuf, proj, ln1g + (size_t)l * DM, ln1b + (size_t)l * DM);
    gemm_tile<<<dim3(16, 6, 1), 256, 0, stream>>>(xbuf, DM, 0, w1l, FF, 0, b1l,
                                                  ffh, FF, 0, DM, 1.f, 1);
    gemm32<<<dim3(8, 12, 1), 256, 0, stream>>>(ffh, FF, 0, w2l, DM, 0, b2l,
                                               proj, DM, 0, FF, 1.f, 0);
    add_ln<<<dim3(NN), 256, 0, stream>>>(xbuf, proj, ln2g + (size_t)l * DM, ln2b + (size_t)l * DM);
  }

  // relation MLP: [U|V] = x @ [W1_rows0:256 | W1_rows256:512], batched z=2
  gemm_tile<<<dim3(8, 6, 2), 256, 0, stream>>>(xbuf, DM, 0,
                                               mw1, HIDN, (long)DM * HIDN,
                                               nullptr,
                                               U, HIDN, (long)NN * HIDN,
                                               DM, 1.f, 0);
  uv_fixup<<<dim3(NN * HIDN / 256), 256, 0, stream>>>(boxes, mw1, mb1, U, V, Vbf);
  // pair GEMM: straight-line wave tasks, no loops, no residency battle
  pair_mfma<<<dim3(24, 192), 512, 0, stream>>>(U, Vbf, w2frag, mb2, out);
}

// Round 9
// 282.279 us; speedup vs baseline: 1.3261x; 1.2600x over previous
//
#include <hip/hip_runtime.h>

#define NN 384
#define DM 256
#define NH 4
#define FF 1024
#define HIDN 512
#define NCLS 56
#define NPAIR (NN*(NN-1))   // 147072

typedef __attribute__((ext_vector_type(8))) short short8v;
typedef __attribute__((ext_vector_type(4))) float f32x4;
typedef __attribute__((ext_vector_type(16))) float f32x16;
typedef __attribute__((ext_vector_type(8))) unsigned short ushort8;
typedef __attribute__((ext_vector_type(4))) unsigned int uint4v;

static __device__ __forceinline__ unsigned short f2bf(float f) {
  unsigned u = __float_as_uint(f);
  unsigned r = u + 0x7fff + ((u >> 16) & 1);   // RNE
  return (unsigned short)(r >> 16);
}
static __device__ __forceinline__ float bf2f(unsigned short v) {
  return __uint_as_float(((unsigned)v) << 16);
}
static __device__ __forceinline__ unsigned cvt_pk_bf16(float lo, float hi) {
  unsigned r;
  asm("v_cvt_pk_bf16_f32 %0, %1, %2" : "=v"(r) : "v"(lo), "v"(hi));
  return r;
}

// ---------------- tiled f32 GEMM 64x64: C = alpha*(A@B) + bias, opt relu ---
__global__ __launch_bounds__(256)
void gemm_tile(const float* __restrict__ A, int lda, long sA,
               const float* __restrict__ B, int ldb, long sB,
               const float* __restrict__ bias,
               float* __restrict__ C, int ldc, long sC,
               int K, float alpha, int relu) {
  __shared__ float As[16][64];
  __shared__ float Bs[16][64];
  A += (size_t)blockIdx.z * sA;
  B += (size_t)blockIdx.z * sB;
  C += (size_t)blockIdx.z * sC;
  int tid = threadIdx.x;
  int tx = tid & 15;
  int ty = tid >> 4;
  int m0 = blockIdx.y * 64;
  int n0 = blockIdx.x * 64;
  int la_r = tid >> 2;
  int la_k = (tid & 3) * 4;
  int lb_k = tid >> 4;
  int lb_n = (tid & 15) * 4;

  float acc[4][4] = {};
  float4 av = *reinterpret_cast<const float4*>(A + (size_t)(m0 + la_r) * lda + la_k);
  float4 bv = *reinterpret_cast<const float4*>(B + (size_t)lb_k * ldb + n0 + lb_n);
  int nchunk = K >> 4;
  for (int ch = 0; ch < nchunk; ++ch) {
    __syncthreads();
    As[la_k + 0][la_r] = av.x;
    As[la_k + 1][la_r] = av.y;
    As[la_k + 2][la_r] = av.z;
    As[la_k + 3][la_r] = av.w;
    *reinterpret_cast<float4*>(&Bs[lb_k][lb_n]) = bv;
    if (ch + 1 < nchunk) {
      int k0 = (ch + 1) << 4;
      av = *reinterpret_cast<const float4*>(A + (size_t)(m0 + la_r) * lda + k0 + la_k);
      bv = *reinterpret_cast<const float4*>(B + (size_t)(k0 + lb_k) * ldb + n0 + lb_n);
    }
    __syncthreads();
    #pragma unroll
    for (int k = 0; k < 16; ++k) {
      float4 a4 = *reinterpret_cast<const float4*>(&As[k][ty * 4]);
      float4 b4 = *reinterpret_cast<const float4*>(&Bs[k][tx * 4]);
      acc[0][0] += a4.x * b4.x; acc[0][1] += a4.x * b4.y; acc[0][2] += a4.x * b4.z; acc[0][3] += a4.x * b4.w;
      acc[1][0] += a4.y * b4.x; acc[1][1] += a4.y * b4.y; acc[1][2] += a4.y * b4.z; acc[1][3] += a4.y * b4.w;
      acc[2][0] += a4.z * b4.x; acc[2][1] += a4.z * b4.y; acc[2][2] += a4.z * b4.z; acc[2][3] += a4.z * b4.w;
      acc[3][0] += a4.w * b4.x; acc[3][1] += a4.w * b4.y; acc[3][2] += a4.w * b4.z; acc[3][3] += a4.w * b4.w;
    }
  }
  float4 bb = make_float4(0.f, 0.f, 0.f, 0.f);
  if (bias) bb = *reinterpret_cast<const float4*>(bias + n0 + tx * 4);
  #pragma unroll
  for (int i = 0; i < 4; ++i) {
    float4 r;
    r.x = acc[i][0] * alpha + bb.x;
    r.y = acc[i][1] * alpha + bb.y;
    r.z = acc[i][2] * alpha + bb.z;
    r.w = acc[i][3] * alpha + bb.w;
    if (relu) {
      r.x = fmaxf(r.x, 0.f); r.y = fmaxf(r.y, 0.f);
      r.z = fmaxf(r.z, 0.f); r.w = fmaxf(r.w, 0.f);
    }
    *reinterpret_cast<float4*>(C + (size_t)(m0 + ty * 4 + i) * ldc + n0 + tx * 4) = r;
  }
}

// ---------------- tiled f32 GEMM 32x32 (more blocks for small outputs) ----
__global__ __launch_bounds__(256)
void gemm32(const float* __restrict__ A, int lda, long sA,
            const float* __restrict__ B, int ldb, long sB,
            const float* __restrict__ bias,
            float* __restrict__ C, int ldc, long sC,
            int K, float alpha, int relu) {
  __shared__ float As[16][33];
  __shared__ float Bs[16][33];
  A += (size_t)blockIdx.z * sA;
  B += (size_t)blockIdx.z * sB;
  C += (size_t)blockIdx.z * sC;
  int tid = threadIdx.x;
  int tx = tid & 15;
  int ty = tid >> 4;
  int m0 = blockIdx.y * 32;
  int n0 = blockIdx.x * 32;
  float acc[2][2] = {};
  int ar = (tid & 127) >> 2;
  int ak = (tid & 3) * 4;
  int bk = (tid & 127) >> 3;
  int bn = ((tid & 127) & 7) * 4;
  bool doA = tid < 128;
  float4 pre;
  if (doA) pre = *reinterpret_cast<const float4*>(A + (size_t)(m0 + ar) * lda + ak);
  else     pre = *reinterpret_cast<const float4*>(B + (size_t)bk * ldb + n0 + bn);
  int nchunk = K >> 4;
  for (int ch = 0; ch < nchunk; ++ch) {
    __syncthreads();
    if (doA) {
      As[ak + 0][ar] = pre.x; As[ak + 1][ar] = pre.y;
      As[ak + 2][ar] = pre.z; As[ak + 3][ar] = pre.w;
    } else {
      Bs[bk][bn + 0] = pre.x; Bs[bk][bn + 1] = pre.y;
      Bs[bk][bn + 2] = pre.z; Bs[bk][bn + 3] = pre.w;
    }
    if (ch + 1 < nchunk) {
      int k0 = (ch + 1) << 4;
      if (doA) pre = *reinterpret_cast<const float4*>(A + (size_t)(m0 + ar) * lda + k0 + ak);
      else     pre = *reinterpret_cast<const float4*>(B + (size_t)(k0 + bk) * ldb + n0 + bn);
    }
    __syncthreads();
    #pragma unroll
    for (int k = 0; k < 16; ++k) {
      float a0 = As[k][ty * 2], a1 = As[k][ty * 2 + 1];
      float b0 = Bs[k][tx * 2], b1 = Bs[k][tx * 2 + 1];
      acc[0][0] += a0 * b0; acc[0][1] += a0 * b1;
      acc[1][0] += a1 * b0; acc[1][1] += a1 * b1;
    }
  }
  float bb0 = 0.f, bb1 = 0.f;
  if (bias) { bb0 = bias[n0 + tx * 2]; bb1 = bias[n0 + tx * 2 + 1]; }
  #pragma unroll
  for (int r = 0; r < 2; ++r) {
    float v0 = acc[r][0] * alpha + bb0;
    float v1 = acc[r][1] * alpha + bb1;
    if (relu) { v0 = fmaxf(v0, 0.f); v1 = fmaxf(v1, 0.f); }
    float2 st = make_float2(v0, v1);
    *reinterpret_cast<float2*>(C + (size_t)(m0 + ty * 2 + r) * ldc + n0 + tx * 2) = st;
  }
}

// ---------------- transpose K heads ---------------------------------------
__global__ __launch_bounds__(256)
void transpose_k(const float* __restrict__ qkv, float* __restrict__ kt) {
  int idx = blockIdx.x * 256 + threadIdx.x;
  int m = idx % NN;
  int d = (idx / NN) & 63;
  int h = idx / (NN * 64);
  kt[idx] = qkv[(size_t)m * 768 + 256 + h * 64 + d];
}

// ---------------- row softmax over 384 ------------------------------------
__global__ __launch_bounds__(128)
void softmax_rows(float* __restrict__ sc) {
  float* row = sc + (size_t)blockIdx.x * NN;
  int t = threadIdx.x;
  float v0 = row[t], v1 = row[t + 128], v2 = row[t + 256];
  __shared__ float red[128];
  float m = fmaxf(v0, fmaxf(v1, v2));
  red[t] = m; __syncthreads();
  for (int s = 64; s > 0; s >>= 1) { if (t < s) red[t] = fmaxf(red[t], red[t + s]); __syncthreads(); }
  m = red[0]; __syncthreads();
  float e0 = expf(v0 - m), e1 = expf(v1 - m), e2 = expf(v2 - m);
  red[t] = e0 + e1 + e2; __syncthreads();
  for (int s = 64; s > 0; s >>= 1) { if (t < s) red[t] += red[t + s]; __syncthreads(); }
  float inv = 1.0f / red[0];
  row[t] = e0 * inv; row[t + 128] = e1 * inv; row[t + 256] = e2 * inv;
}

// ---------------- residual add + LayerNorm --------------------------------
__global__ __launch_bounds__(256)
void add_ln(float* __restrict__ x, const float* __restrict__ r,
            const float* __restrict__ g, const float* __restrict__ b) {
  int i = blockIdx.x, t = threadIdx.x;
  float v = x[(size_t)i * DM + t] + r[(size_t)i * DM + t];
  __shared__ float red[256];
  red[t] = v; __syncthreads();
  for (int s = 128; s > 0; s >>= 1) { if (t < s) red[t] += red[t + s]; __syncthreads(); }
  float mu = red[0] * (1.0f / DM); __syncthreads();
  float dv = v - mu;
  red[t] = dv * dv; __syncthreads();
  for (int s = 128; s > 0; s >>= 1) { if (t < s) red[t] += red[t + s]; __syncthreads(); }
  float var = red[0] * (1.0f / DM);
  float inv = rsqrtf(var + 1e-5f);
  x[(size_t)i * DM + t] = dv * inv * g[t] + b[t];
}

// ------ add box terms + b1; U stays f32, V goes to global bf16 ------------
__global__ __launch_bounds__(256)
void uv_fixup(const float* __restrict__ boxes, const float* __restrict__ w1,
              const float* __restrict__ b1,
              float* __restrict__ U, const float* __restrict__ V,
              unsigned short* __restrict__ Vbf) {
  int idx = blockIdx.x * 256 + threadIdx.x;   // NN*HIDN
  int i = idx >> 9, k = idx & 511;
  float u = U[idx] + b1[k], v = V[idx];
  #pragma unroll
  for (int c = 0; c < 4; ++c) {
    float bv = boxes[i * 4 + c];
    u += bv * w1[(size_t)(512 + c) * HIDN + k];
    v += bv * w1[(size_t)(516 + c) * HIDN + k];
  }
  U[idx] = u;
  Vbf[idx] = f2bf(v);
}

// ------ pack W2 into 32x32x16 MFMA B-fragment order (bf16) ----------------
// lane l holds B[k = ks*16 + (l>>5)*8 + r][n = nt*32 + (l&31)], r=0..7
// layout: frag[((ks*2 + nt)*64 + l)*8 + r];  ks 0..31, nt 0..1  -> 64KB
__global__ __launch_bounds__(256)
void prep_w2frag(const float* __restrict__ w2, unsigned short* __restrict__ frag) {
  int idx = blockIdx.x * 256 + threadIdx.x;   // 32*2*64 = 4096
  int l = idx & 63;
  int nt = (idx >> 6) & 1;
  int ks = idx >> 7;
  int kb = ks * 16 + ((l >> 5) * 8);
  int n = nt * 32 + (l & 31);
  #pragma unroll
  for (int r = 0; r < 8; ++r) {
    float v = (n < NCLS) ? w2[(size_t)(kb + r) * NCLS + n] : 0.f;
    frag[(size_t)idx * 8 + r] = f2bf(v);
  }
}

// ---------------- pair indices output -------------------------------------
__global__ __launch_bounds__(256)
void pair_idx_kernel(float* __restrict__ out) {
  int p = blockIdx.x * 256 + threadIdx.x;
  if (p >= NPAIR) return;
  int i = p / (NN - 1);
  int r = p - i * (NN - 1);
  int j = r + (r >= i ? 1 : 0);
  out[2 * p + 0] = (float)i;
  out[2 * p + 1] = (float)j;
}

// ---------------- pair MLP via MFMA v7: 32x32x16, streamed B --------------
// One wave-task = (i, 32 j's, ALL 56 classes). Per k-step: build ONE A-frag
// (row = lane&31 -> j; k = ks*16 + (lane>>5)*8 + r) from Vbf (16B) + U (32B,
// 2 distinct addrs/wave -> broadcast), then 2 MFMAs with B-frags STREAMED
// from the 64KB L2-resident w2frag. Loop carries only acc (32 VGPR) -- no
// loop-invariant fragment arrays for the allocator to spill (r5-r8 lesson).
// Build done ONCE per (i,j,k) (v6 did it 4x across class-tile waves).
__global__ __launch_bounds__(256)
void pair_mfma(const float* __restrict__ U, const unsigned short* __restrict__ Vbf,
               const unsigned short* __restrict__ w2frag,
               const float* __restrict__ b2, float* __restrict__ out) {
  int tid = threadIdx.x;
  int wave = tid >> 6;
  int lane = tid & 63;
  int bx = blockIdx.x;                 // 0..1151
  int i = bx / 3;                      // 0..383
  int jt = (bx % 3) * 4 + wave;        // 0..11 (32 j's each)

  int col = lane & 31;
  int half = lane >> 5;                // 0 or 1
  int j_row = jt * 32 + col;

  const unsigned short* vsrc = Vbf + (size_t)j_row * HIDN + half * 8;
  const float* usrc = U + (size_t)i * HIDN + half * 8;
  const unsigned short* bsrc = w2frag + (size_t)lane * 8;

  f32x16 acc0 = {};
  f32x16 acc1 = {};
  #pragma unroll
  for (int ks = 0; ks < 32; ++ks) {
    ushort8 v8 = *reinterpret_cast<const ushort8*>(vsrc + ks * 16);
    float4 ua = *reinterpret_cast<const float4*>(usrc + ks * 16);
    float4 ub = *reinterpret_cast<const float4*>(usrc + ks * 16 + 4);
    short8v b0 = *reinterpret_cast<const short8v*>(bsrc + (size_t)(ks * 2 + 0) * 512);
    short8v b1 = *reinterpret_cast<const short8v*>(bsrc + (size_t)(ks * 2 + 1) * 512);
    float h0 = fmaxf(bf2f(v8[0]) + ua.x, 0.f);
    float h1 = fmaxf(bf2f(v8[1]) + ua.y, 0.f);
    float h2 = fmaxf(bf2f(v8[2]) + ua.z, 0.f);
    float h3 = fmaxf(bf2f(v8[3]) + ua.w, 0.f);
    float h4 = fmaxf(bf2f(v8[4]) + ub.x, 0.f);
    float h5 = fmaxf(bf2f(v8[5]) + ub.y, 0.f);
    float h6 = fmaxf(bf2f(v8[6]) + ub.z, 0.f);
    float h7 = fmaxf(bf2f(v8[7]) + ub.w, 0.f);
    uint4v pk;
    pk[0] = cvt_pk_bf16(h0, h1);
    pk[1] = cvt_pk_bf16(h2, h3);
    pk[2] = cvt_pk_bf16(h4, h5);
    pk[3] = cvt_pk_bf16(h6, h7);
    short8v a = *reinterpret_cast<short8v*>(&pk);
    acc0 = __builtin_amdgcn_mfma_f32_32x32x16_bf16(a, b0, acc0, 0, 0, 0);
    acc1 = __builtin_amdgcn_mfma_f32_32x32x16_bf16(a, b1, acc1, 0, 0, 0);
  }

  float b2v0 = b2[col];                                  // col < 32 < 56
  float b2v1 = (32 + col < NCLS) ? b2[32 + col] : 0.f;
  float* lg = out + 2 * (size_t)NPAIR;
  #pragma unroll
  for (int reg = 0; reg < 16; ++reg) {
    int jl = (reg & 3) + 8 * (reg >> 2) + 4 * half;      // 0..31, unique
    int j = jt * 32 + jl;
    if (j != i) {
      int p = i * (NN - 1) + (j > i ? j - 1 : j);
      float* row = lg + (size_t)p * NCLS;
      row[col] = acc0[reg] + b2v0;
      if (col < NCLS - 32) row[32 + col] = acc1[reg] + b2v1;
    }
  }
}

// --------------------------------------------------------------------------
extern "C" void kernel_launch(void* const* d_in, const int* in_sizes, int n_in,
                              void* d_out, int out_size, void* d_ws, size_t ws_size,
                              hipStream_t stream) {
  const float* node   = (const float*)d_in[0];
  const float* boxes  = (const float*)d_in[1];
  const float* w_in   = (const float*)d_in[2];
  const float* b_in   = (const float*)d_in[3];
  const float* w_out  = (const float*)d_in[4];
  const float* b_out  = (const float*)d_in[5];
  const float* fw1    = (const float*)d_in[6];
  const float* fb1    = (const float*)d_in[7];
  const float* fw2    = (const float*)d_in[8];
  const float* fb2    = (const float*)d_in[9];
  const float* ln1g   = (const float*)d_in[10];
  const float* ln1b   = (const float*)d_in[11];
  const float* ln2g   = (const float*)d_in[12];
  const float* ln2b   = (const float*)d_in[13];
  const float* mw1    = (const float*)d_in[14];
  const float* mb1    = (const float*)d_in[15];
  const float* mw2    = (const float*)d_in[16];
  const float* mb2    = (const float*)d_in[17];
  float* out = (float*)d_out;

  float* ws = (float*)d_ws;
  float* xbuf  = ws;                   // 384*256
  float* qkv   = xbuf  + 98304;        // 384*768
  float* sc    = qkv   + 294912;       // 4*384*384
  float* attno = sc    + 589824;       // 384*256
  float* proj  = attno + 98304;        // 384*256
  float* ffh   = proj  + 98304;        // 384*1024
  float* U     = ffh   + 393216;       // 384*512
  float* V     = U     + 196608;       // 384*512  (must follow U contiguously)
  unsigned short* Vbf    = (unsigned short*)(V + 196608);    // 384*512 bf16
  unsigned short* w2frag = (unsigned short*)(V + 294912);    // 64KB
  float* kt    = V + 327680;                                 // 4*64*384

  hipMemcpyAsync(xbuf, node, (size_t)NN * DM * sizeof(float),
                 hipMemcpyDeviceToDevice, stream);
  prep_w2frag<<<dim3(16), 256, 0, stream>>>(mw2, w2frag);
  pair_idx_kernel<<<dim3((NPAIR + 255) / 256), 256, 0, stream>>>(out);

  for (int l = 0; l < 2; ++l) {
    const float* wi  = w_in  + (size_t)l * DM * 768;
    const float* bi  = b_in  + (size_t)l * 768;
    const float* wo  = w_out + (size_t)l * DM * DM;
    const float* bo  = b_out + (size_t)l * DM;
    const float* w1l = fw1   + (size_t)l * DM * FF;
    const float* b1l = fb1   + (size_t)l * FF;
    const float* w2l = fw2   + (size_t)l * FF * DM;
    const float* b2l = fb2   + (size_t)l * DM;

    gemm_tile<<<dim3(12, 6, 1), 256, 0, stream>>>(xbuf, DM, 0, wi, 768, 0, bi,
                                                  qkv, 768, 0, DM, 1.f, 0);
    transpose_k<<<dim3(384), 256, 0, stream>>>(qkv, kt);
    gemm_tile<<<dim3(6, 6, NH), 256, 0, stream>>>(qkv, 768, 64, kt, NN, 64 * NN,
                                                  nullptr, sc, NN, (long)NN * NN,
                                                  64, 0.125f, 0);
    softmax_rows<<<dim3(NH * NN), 128, 0, stream>>>(sc);
    gemm32<<<dim3(2, 12, NH), 256, 0, stream>>>(sc, NN, (long)NN * NN,
                                                qkv + 512, 768, 64, nullptr,
                                                attno, DM, 64, NN, 1.f, 0);
    gemm32<<<dim3(8, 12, 1), 256, 0, stream>>>(attno, DM, 0, wo, DM, 0, bo,
                                               proj, DM, 0, DM, 1.f, 0);
    add_ln<<<dim3(NN), 256, 0, stream>>>(xbuf, proj, ln1g + (size_t)l * DM, ln1b + (size_t)l * DM);
    gemm_tile<<<dim3(16, 6, 1), 256, 0, stream>>>(xbuf, DM, 0, w1l, FF, 0, b1l,
                                                  ffh, FF, 0, DM, 1.f, 1);
    gemm32<<<dim3(8, 12, 1), 256, 0, stream>>>(ffh, FF, 0, w2l, DM, 0, b2l,
                                               proj, DM, 0, FF, 1.f, 0);
    add_ln<<<dim3(NN), 256, 0, stream>>>(xbuf, proj, ln2g + (size_t)l * DM, ln2b + (size_t)l * DM);
  }

  // relation MLP: [U|V] = x @ [W1_rows0:256 | W1_rows256:512], batched z=2
  gemm_tile<<<dim3(8, 6, 2), 256, 0, stream>>>(xbuf, DM, 0,
                                               mw1, HIDN, (long)DM * HIDN,
                                               nullptr,
                                               U, HIDN, (long)NN * HIDN,
                                               DM, 1.f, 0);
  uv_fixup<<<dim3(NN * HIDN / 256), 256, 0, stream>>>(boxes, mw1, mb1, U, V, Vbf);
  // pair GEMM: 32x32x16 MFMA, streamed B, build-once
  pair_mfma<<<dim3(1152), 256, 0, stream>>>(U, Vbf, w2frag, mb2, out);
}

// Round 10
// 270.446 us; speedup vs baseline: 1.3841x; 1.0438x over previous
//
#include <hip/hip_runtime.h>

#define NN 384
#define DM 256
#define NH 4
#define FF 1024
#define HIDN 512
#define NCLS 56
#define NPAIR (NN*(NN-1))   // 147072

typedef __attribute__((ext_vector_type(8))) short short8v;
typedef __attribute__((ext_vector_type(4))) float f32x4;
typedef __attribute__((ext_vector_type(16))) float f32x16;
typedef __attribute__((ext_vector_type(8))) unsigned short ushort8;
typedef __attribute__((ext_vector_type(4))) unsigned int uint4v;

static __device__ __forceinline__ unsigned short f2bf(float f) {
  unsigned u = __float_as_uint(f);
  unsigned r = u + 0x7fff + ((u >> 16) & 1);   // RNE
  return (unsigned short)(r >> 16);
}
static __device__ __forceinline__ float bf2f(unsigned short v) {
  return __uint_as_float(((unsigned)v) << 16);
}
static __device__ __forceinline__ unsigned cvt_pk_bf16(float lo, float hi) {
  unsigned r;
  asm("v_cvt_pk_bf16_f32 %0, %1, %2" : "=v"(r) : "v"(lo), "v"(hi));
  return r;
}
// C/D row for 32x32x16 MFMA (v7-verified): ml = (reg&3)+8*(reg>>2)+4*half
#define MLROW(reg, half) (((reg) & 3) + 8 * ((reg) >> 2) + 4 * (half))

// ===== pack ALL weights into 32x32x16 B-fragment order (bf16) ==============
// frag element (ks, nt, lane, r) -> B[ks*16 + (lane>>5)*8 + r][nt*32 + (lane&31)]
// stored at ((ks*Nt + nt)*64 + lane)*8 + r
__global__ __launch_bounds__(256)
void pack_all(const float* __restrict__ wi, const float* __restrict__ wo,
              const float* __restrict__ w1, const float* __restrict__ w2,
              const float* __restrict__ mw1, const float* __restrict__ mw2,
              unsigned short* __restrict__ wi_f, unsigned short* __restrict__ wo_f,
              unsigned short* __restrict__ w1_f, unsigned short* __restrict__ w2_f,
              unsigned short* __restrict__ mw1_f, unsigned short* __restrict__ mw2_f) {
  int y = blockIdx.y, z = blockIdx.z;
  int t = blockIdx.x * 256 + threadIdx.x;
  const float* src; unsigned short* dst; int K, N; long sS, sD;
  switch (y) {
    case 0: src = wi;  dst = wi_f;  K = 256;  N = 768;  sS = 256L*768;  sD = 196608; break;
    case 1: src = wo;  dst = wo_f;  K = 256;  N = 256;  sS = 256L*256;  sD = 65536;  break;
    case 2: src = w1;  dst = w1_f;  K = 256;  N = 1024; sS = 256L*1024; sD = 262144; break;
    case 3: src = w2;  dst = w2_f;  K = 1024; N = 256;  sS = 1024L*256; sD = 262144; break;
    case 4: src = mw1; dst = mw1_f; K = 256;  N = 512;  sS = 256L*512;  sD = 131072; break;
    default: {   // mw2 [512,56] -> Nt=2 padded to 64 cols, ks=32
      if (z || t >= 4096) return;
      int l = t & 63, nt = (t >> 6) & 1, ks = t >> 7;
      int kb = ks * 16 + ((l >> 5) * 8), n = nt * 32 + (l & 31);
      #pragma unroll
      for (int r = 0; r < 8; ++r) {
        float v = (n < NCLS) ? mw2[(size_t)(kb + r) * NCLS + n] : 0.f;
        mw2_f[(size_t)t * 8 + r] = f2bf(v);
      }
      return;
    }
  }
  int Nt = N >> 5;
  int total = (K >> 4) * Nt * 64;
  if (t >= total) return;
  src += z * sS; dst += z * sD;
  int l = t & 63;
  int rem = t >> 6;
  int nt = rem % Nt, ks = rem / Nt;
  int kb = ks * 16 + ((l >> 5) * 8), n = nt * 32 + (l & 31);
  #pragma unroll
  for (int r = 0; r < 8; ++r)
    dst[(size_t)t * 8 + r] = f2bf(src[(size_t)(kb + r) * N + n]);
}

// ===== init: node -> xbuf f32 + x_bf bf16 ===================================
__global__ __launch_bounds__(256)
void x_init(const float* __restrict__ node, float* __restrict__ xbuf,
            unsigned short* __restrict__ xbf) {
  int i = blockIdx.x * 256 + threadIdx.x;   // 98304
  float v = node[i];
  xbuf[i] = v;
  xbf[i] = f2bf(v);
}

// ===== QKV projection: x_bf @ wi + bi; writes QK row-major + V transposed ==
__global__ __launch_bounds__(256)
void qkv_mfma(const unsigned short* __restrict__ xbf, const unsigned short* __restrict__ wif,
              const float* __restrict__ bi, unsigned short* __restrict__ qk,
              unsigned short* __restrict__ vt) {
  int id = blockIdx.x * 4 + (threadIdx.x >> 6);   // 0..287 (12 mt x 24 nt)
  int lane = threadIdx.x & 63;
  int mt = id % 12, nt = id / 12;
  int col = lane & 31, half = lane >> 5;
  const unsigned short* asrc = xbf + (size_t)(mt * 32 + col) * 256 + half * 8;
  const unsigned short* bsrc = wif + ((size_t)nt * 64 + lane) * 8;
  f32x16 acc = {};
  #pragma unroll
  for (int ks = 0; ks < 16; ++ks) {
    short8v a = *reinterpret_cast<const short8v*>(asrc + ks * 16);
    short8v b = *reinterpret_cast<const short8v*>(bsrc + (size_t)ks * 24 * 512);
    acc = __builtin_amdgcn_mfma_f32_32x32x16_bf16(a, b, acc, 0, 0, 0);
  }
  int n = nt * 32 + col;
  float bb = bi[n];
  #pragma unroll
  for (int reg = 0; reg < 16; ++reg) {
    int row = mt * 32 + MLROW(reg, half);
    float v = acc[reg] + bb;
    if (n < 512) qk[(size_t)row * 512 + n] = f2bf(v);         // Q | K
    else         vt[(size_t)(n - 512) * 384 + row] = f2bf(v); // V^T [256][384]
  }
}

// ===== fused attention: S = QK^T/8 -> softmax -> O = P@V ===================
// block = (n-tile of 64, head). LDS: S f32 [64][385] + P bf16 [64][392].
__global__ __launch_bounds__(256)
void fused_attn(const unsigned short* __restrict__ qk, const unsigned short* __restrict__ vt,
                unsigned short* __restrict__ attno) {
  __shared__ float S[64][385];
  __shared__ unsigned short P[64][392];
  int n0 = blockIdx.x * 64;
  int h = blockIdx.y;
  int wave = threadIdx.x >> 6, lane = threadIdx.x & 63;
  int col = lane & 31, half = lane >> 5;
  // phase 1: scores
  {
    int mt = wave & 1;
    const unsigned short* asrc = qk + (size_t)(n0 + mt * 32 + col) * 512 + h * 64 + half * 8;
    #pragma unroll
    for (int j = 0; j < 6; ++j) {
      int ntk = (wave >> 1) + j * 2;
      const unsigned short* bsrc = qk + (size_t)(ntk * 32 + col) * 512 + 256 + h * 64 + half * 8;
      f32x16 acc = {};
      #pragma unroll
      for (int ks = 0; ks < 4; ++ks) {
        short8v a = *reinterpret_cast<const short8v*>(asrc + ks * 16);
        short8v b = *reinterpret_cast<const short8v*>(bsrc + ks * 16);
        acc = __builtin_amdgcn_mfma_f32_32x32x16_bf16(a, b, acc, 0, 0, 0);
      }
      #pragma unroll
      for (int reg = 0; reg < 16; ++reg)
        S[mt * 32 + MLROW(reg, half)][ntk * 32 + col] = acc[reg] * 0.125f;
    }
  }
  __syncthreads();
  // phase 2: softmax (4 threads per row)
  {
    int row = threadIdx.x >> 2, q = threadIdx.x & 3;
    float mx = -1e30f;
    #pragma unroll 8
    for (int c = 0; c < 96; ++c) mx = fmaxf(mx, S[row][q * 96 + c]);
    mx = fmaxf(mx, __shfl_xor(mx, 1));
    mx = fmaxf(mx, __shfl_xor(mx, 2));
    float sum = 0.f;
    #pragma unroll 8
    for (int c = 0; c < 96; ++c) {
      float e = __expf(S[row][q * 96 + c] - mx);
      S[row][q * 96 + c] = e;
      sum += e;
    }
    sum += __shfl_xor(sum, 1);
    sum += __shfl_xor(sum, 2);
    float inv = 1.0f / sum;
    #pragma unroll 8
    for (int c = 0; c < 96; ++c)
      P[row][q * 96 + c] = f2bf(S[row][q * 96 + c] * inv);
  }
  __syncthreads();
  // phase 3: O = P @ V  (B-frags are V^T row loads)
  {
    int mt = wave & 1, ntd = wave >> 1;
    const unsigned short* bsrc = vt + (size_t)(h * 64 + ntd * 32 + col) * 384 + half * 8;
    f32x16 acc = {};
    #pragma unroll
    for (int ks = 0; ks < 24; ++ks) {
      short8v a = *reinterpret_cast<const short8v*>(&P[mt * 32 + col][ks * 16 + half * 8]);
      short8v b = *reinterpret_cast<const short8v*>(bsrc + ks * 16);
      acc = __builtin_amdgcn_mfma_f32_32x32x16_bf16(a, b, acc, 0, 0, 0);
    }
    #pragma unroll
    for (int reg = 0; reg < 16; ++reg)
      attno[(size_t)(n0 + mt * 32 + MLROW(reg, half)) * 256 + h * 64 + ntd * 32 + col] =
          f2bf(acc[reg]);
  }
}

// ===== fused GEMM(+bias) + residual + LayerNorm ============================
// block = 64-row stripe (6 blocks). A bf16 [384,K], N=256. Writes xres f32 + xbf.
template<int NKS>
__global__ __launch_bounds__(256)
void gemm_ln(const unsigned short* __restrict__ A, int lda,
             const unsigned short* __restrict__ Bfrag,
             const float* __restrict__ bias,
             float* __restrict__ xres, unsigned short* __restrict__ xbf,
             const float* __restrict__ gamma, const float* __restrict__ beta) {
  __shared__ float cs[64][261];
  int r0 = blockIdx.x * 64;
  int wave = threadIdx.x >> 6, lane = threadIdx.x & 63;
  int mt = wave & 1, ntg = wave >> 1;   // nts = ntg*4 .. +3
  int col = lane & 31, half = lane >> 5;
  const unsigned short* asrc = A + (size_t)(r0 + mt * 32 + col) * lda + half * 8;
  const unsigned short* bb = Bfrag + (size_t)lane * 8;
  f32x16 ac0 = {}, ac1 = {}, ac2 = {}, ac3 = {};
  #pragma unroll 8
  for (int ks = 0; ks < NKS; ++ks) {
    short8v a = *reinterpret_cast<const short8v*>(asrc + ks * 16);
    size_t bo = (size_t)ks * 8 * 512;
    ac0 = __builtin_amdgcn_mfma_f32_32x32x16_bf16(a, *reinterpret_cast<const short8v*>(bb + bo + (size_t)(ntg * 4 + 0) * 512), ac0, 0, 0, 0);
    ac1 = __builtin_amdgcn_mfma_f32_32x32x16_bf16(a, *reinterpret_cast<const short8v*>(bb + bo + (size_t)(ntg * 4 + 1) * 512), ac1, 0, 0, 0);
    ac2 = __builtin_amdgcn_mfma_f32_32x32x16_bf16(a, *reinterpret_cast<const short8v*>(bb + bo + (size_t)(ntg * 4 + 2) * 512), ac2, 0, 0, 0);
    ac3 = __builtin_amdgcn_mfma_f32_32x32x16_bf16(a, *reinterpret_cast<const short8v*>(bb + bo + (size_t)(ntg * 4 + 3) * 512), ac3, 0, 0, 0);
  }
  #pragma unroll
  for (int reg = 0; reg < 16; ++reg) {
    int r = mt * 32 + MLROW(reg, half);
    int c0 = ntg * 128 + col;
    cs[r][c0 +  0] = ac0[reg] + bias[c0];
    cs[r][c0 + 32] = ac1[reg] + bias[c0 + 32];
    cs[r][c0 + 64] = ac2[reg] + bias[c0 + 64];
    cs[r][c0 + 96] = ac3[reg] + bias[c0 + 96];
  }
  __syncthreads();
  int row = threadIdx.x >> 2, q = threadIdx.x & 3;
  const float* res = xres + (size_t)(r0 + row) * 256 + q * 64;
  float s = 0.f, s2 = 0.f;
  #pragma unroll 8
  for (int c = 0; c < 64; ++c) {
    float v = cs[row][q * 64 + c] + res[c];
    s += v; s2 += v * v;
  }
  s  += __shfl_xor(s, 1);  s  += __shfl_xor(s, 2);
  s2 += __shfl_xor(s2, 1); s2 += __shfl_xor(s2, 2);
  float mu = s * (1.0f / 256.0f);
  float var = s2 * (1.0f / 256.0f) - mu * mu;
  float inv = rsqrtf(var + 1e-5f);
  float* xo = xres + (size_t)(r0 + row) * 256 + q * 64;
  unsigned short* xb = xbf + (size_t)(r0 + row) * 256 + q * 64;
  #pragma unroll 8
  for (int c = 0; c < 64; ++c) {
    float v = cs[row][q * 64 + c] + res[c];
    float o = (v - mu) * inv * gamma[q * 64 + c] + beta[q * 64 + c];
    xo[c] = o;
    xb[c] = f2bf(o);
  }
}

// ===== generic MFMA GEMM, one wave per 32x32 tile ==========================
template<int OUT_BF16, int RELU, int NKS, int NT>
__global__ __launch_bounds__(256)
void mfma_gemm(const unsigned short* __restrict__ A, int lda, long sA,
               const unsigned short* __restrict__ Bfrag, long sB,
               const float* __restrict__ bias,
               float* __restrict__ Cf, unsigned short* __restrict__ Cb,
               int ldc, long sC, int Mt) {
  int id = blockIdx.x * 4 + (threadIdx.x >> 6);
  if (id >= Mt * NT) return;
  int lane = threadIdx.x & 63;
  int mt = id % Mt, nt = id / Mt;
  int z = blockIdx.z;
  int col = lane & 31, half = lane >> 5;
  const unsigned short* asrc = A + z * sA + (size_t)(mt * 32 + col) * lda + half * 8;
  const unsigned short* bsrc = Bfrag + z * sB + ((size_t)nt * 64 + lane) * 8;
  f32x16 acc = {};
  #pragma unroll
  for (int ks = 0; ks < NKS; ++ks) {
    short8v a = *reinterpret_cast<const short8v*>(asrc + ks * 16);
    short8v b = *reinterpret_cast<const short8v*>(bsrc + (size_t)ks * NT * 512);
    acc = __builtin_amdgcn_mfma_f32_32x32x16_bf16(a, b, acc, 0, 0, 0);
  }
  int n = nt * 32 + col;
  float bb = bias ? bias[n] : 0.f;
  #pragma unroll
  for (int reg = 0; reg < 16; ++reg) {
    int row = mt * 32 + MLROW(reg, half);
    float v = acc[reg] + bb;
    if (RELU) v = fmaxf(v, 0.f);
    if (OUT_BF16) Cb[z * sC + (size_t)row * ldc + n] = f2bf(v);
    else          Cf[z * sC + (size_t)row * ldc + n] = v;
  }
}

// ===== relation-head helpers (unchanged from r9) ===========================
__global__ __launch_bounds__(256)
void uv_fixup(const float* __restrict__ boxes, const float* __restrict__ w1,
              const float* __restrict__ b1,
              float* __restrict__ U, const float* __restrict__ V,
              unsigned short* __restrict__ Vbf) {
  int idx = blockIdx.x * 256 + threadIdx.x;   // NN*HIDN
  int i = idx >> 9, k = idx & 511;
  float u = U[idx] + b1[k], v = V[idx];
  #pragma unroll
  for (int c = 0; c < 4; ++c) {
    float bv = boxes[i * 4 + c];
    u += bv * w1[(size_t)(512 + c) * HIDN + k];
    v += bv * w1[(size_t)(516 + c) * HIDN + k];
  }
  U[idx] = u;
  Vbf[idx] = f2bf(v);
}

__global__ __launch_bounds__(256)
void pair_idx_kernel(float* __restrict__ out) {
  int p = blockIdx.x * 256 + threadIdx.x;
  if (p >= NPAIR) return;
  int i = p / (NN - 1);
  int r = p - i * (NN - 1);
  int j = r + (r >= i ? 1 : 0);
  out[2 * p + 0] = (float)i;
  out[2 * p + 1] = (float)j;
}

// pair MLP v7: 32x32x16, streamed B, build-once (r9: 47us)
__global__ __launch_bounds__(256)
void pair_mfma(const float* __restrict__ U, const unsigned short* __restrict__ Vbf,
               const unsigned short* __restrict__ w2frag,
               const float* __restrict__ b2, float* __restrict__ out) {
  int tid = threadIdx.x;
  int wave = tid >> 6;
  int lane = tid & 63;
  int bx = blockIdx.x;
  int i = bx / 3;
  int jt = (bx % 3) * 4 + wave;

  int col = lane & 31;
  int half = lane >> 5;
  int j_row = jt * 32 + col;

  const unsigned short* vsrc = Vbf + (size_t)j_row * HIDN + half * 8;
  const float* usrc = U + (size_t)i * HIDN + half * 8;
  const unsigned short* bsrc = w2frag + (size_t)lane * 8;

  f32x16 acc0 = {};
  f32x16 acc1 = {};
  #pragma unroll
  for (int ks = 0; ks < 32; ++ks) {
    ushort8 v8 = *reinterpret_cast<const ushort8*>(vsrc + ks * 16);
    float4 ua = *reinterpret_cast<const float4*>(usrc + ks * 16);
    float4 ub = *reinterpret_cast<const float4*>(usrc + ks * 16 + 4);
    short8v b0 = *reinterpret_cast<const short8v*>(bsrc + (size_t)(ks * 2 + 0) * 512);
    short8v b1 = *reinterpret_cast<const short8v*>(bsrc + (size_t)(ks * 2 + 1) * 512);
    float h0 = fmaxf(bf2f(v8[0]) + ua.x, 0.f);
    float h1 = fmaxf(bf2f(v8[1]) + ua.y, 0.f);
    float h2 = fmaxf(bf2f(v8[2]) + ua.z, 0.f);
    float h3 = fmaxf(bf2f(v8[3]) + ua.w, 0.f);
    float h4 = fmaxf(bf2f(v8[4]) + ub.x, 0.f);
    float h5 = fmaxf(bf2f(v8[5]) + ub.y, 0.f);
    float h6 = fmaxf(bf2f(v8[6]) + ub.z, 0.f);
    float h7 = fmaxf(bf2f(v8[7]) + ub.w, 0.f);
    uint4v pk;
    pk[0] = cvt_pk_bf16(h0, h1);
    pk[1] = cvt_pk_bf16(h2, h3);
    pk[2] = cvt_pk_bf16(h4, h5);
    pk[3] = cvt_pk_bf16(h6, h7);
    short8v a = *reinterpret_cast<short8v*>(&pk);
    acc0 = __builtin_amdgcn_mfma_f32_32x32x16_bf16(a, b0, acc0, 0, 0, 0);
    acc1 = __builtin_amdgcn_mfma_f32_32x32x16_bf16(a, b1, acc1, 0, 0, 0);
  }

  float b2v0 = b2[col];
  float b2v1 = (32 + col < NCLS) ? b2[32 + col] : 0.f;
  float* lg = out + 2 * (size_t)NPAIR;
  #pragma unroll
  for (int reg = 0; reg < 16; ++reg) {
    int jl = MLROW(reg, half);
    int j = jt * 32 + jl;
    if (j != i) {
      int p = i * (NN - 1) + (j > i ? j - 1 : j);
      float* row = lg + (size_t)p * NCLS;
      row[col] = acc0[reg] + b2v0;
      if (col < NCLS - 32) row[32 + col] = acc1[reg] + b2v1;
    }
  }
}

// ===========================================================================
extern "C" void kernel_launch(void* const* d_in, const int* in_sizes, int n_in,
                              void* d_out, int out_size, void* d_ws, size_t ws_size,
                              hipStream_t stream) {
  const float* node   = (const float*)d_in[0];
  const float* boxes  = (const float*)d_in[1];
  const float* w_in   = (const float*)d_in[2];
  const float* b_in   = (const float*)d_in[3];
  const float* w_out  = (const float*)d_in[4];
  const float* b_out  = (const float*)d_in[5];
  const float* fw1    = (const float*)d_in[6];
  const float* fb1    = (const float*)d_in[7];
  const float* fw2    = (const float*)d_in[8];
  const float* fb2    = (const float*)d_in[9];
  const float* ln1g   = (const float*)d_in[10];
  const float* ln1b   = (const float*)d_in[11];
  const float* ln2g   = (const float*)d_in[12];
  const float* ln2b   = (const float*)d_in[13];
  const float* mw1    = (const float*)d_in[14];
  const float* mb1    = (const float*)d_in[15];
  const float* mw2    = (const float*)d_in[16];
  const float* mb2    = (const float*)d_in[17];
  float* out = (float*)d_out;

  float* ws = (float*)d_ws;
  float* xbuf = ws;                    // 98304 f32
  float* U    = xbuf + 98304;          // 196608 f32
  float* V    = U + 196608;            // 196608 f32
  unsigned short* us = (unsigned short*)(V + 196608);
  unsigned short* x_bf   = us;             us += 98304;
  unsigned short* qk_bf  = us;             us += 196608;   // [384][512]
  unsigned short* vt_bf  = us;             us += 98304;    // [256][384]
  unsigned short* at_bf  = us;             us += 98304;    // [384][256]
  unsigned short* ffh_bf = us;             us += 393216;   // [384][1024]
  unsigned short* Vbf    = us;             us += 196608;   // [384][512]
  unsigned short* wi_f   = us;             us += 393216;   // 2 x 196608
  unsigned short* wo_f   = us;             us += 131072;   // 2 x 65536
  unsigned short* fw1_f  = us;             us += 524288;   // 2 x 262144
  unsigned short* fw2_f  = us;             us += 524288;   // 2 x 262144
  unsigned short* mw1_f  = us;             us += 262144;   // 2 x 131072
  unsigned short* w2_f   = us;             us += 32768;

  // one-time prep
  pack_all<<<dim3(128, 6, 2), 256, 0, stream>>>(w_in, w_out, fw1, fw2, mw1, mw2,
                                                wi_f, wo_f, fw1_f, fw2_f, mw1_f, w2_f);
  pair_idx_kernel<<<dim3((NPAIR + 255) / 256), 256, 0, stream>>>(out);
  x_init<<<dim3(384), 256, 0, stream>>>(node, xbuf, x_bf);

  for (int l = 0; l < 2; ++l) {
    qkv_mfma<<<dim3(72), 256, 0, stream>>>(x_bf, wi_f + (size_t)l * 196608,
                                           b_in + (size_t)l * 768, qk_bf, vt_bf);
    fused_attn<<<dim3(6, 4), 256, 0, stream>>>(qk_bf, vt_bf, at_bf);
    gemm_ln<16><<<dim3(6), 256, 0, stream>>>(at_bf, 256, wo_f + (size_t)l * 65536,
                                             b_out + (size_t)l * 256, xbuf, x_bf,
                                             ln1g + (size_t)l * 256, ln1b + (size_t)l * 256);
    mfma_gemm<1, 1, 16, 32><<<dim3(96), 256, 0, stream>>>(
        x_bf, 256, 0, fw1_f + (size_t)l * 262144, 0, fb1 + (size_t)l * 1024,
        nullptr, ffh_bf, 1024, 0, 12);
    gemm_ln<64><<<dim3(6), 256, 0, stream>>>(ffh_bf, 1024, fw2_f + (size_t)l * 262144,
                                             fb2 + (size_t)l * 256, xbuf, x_bf,
                                             ln2g + (size_t)l * 256, ln2b + (size_t)l * 256);
  }

  // relation head: U,V = x @ mw1 halves (batched z=2), then fixup + pair GEMM
  mfma_gemm<0, 0, 16, 16><<<dim3(48, 1, 2), 256, 0, stream>>>(
      x_bf, 256, 0, mw1_f, 131072, nullptr, U, nullptr, 512, 196608, 12);
  uv_fixup<<<dim3(NN * HIDN / 256), 256, 0, stream>>>(boxes, mw1, mb1, U, V, Vbf);
  pair_mfma<<<dim3(1152), 256, 0, stream>>>(U, Vbf, w2_f, mb2, out);
}

// Round 11
// 173.761 us; speedup vs baseline: 2.1543x; 1.5564x over previous
//
#include <hip/hip_runtime.h>

#define NN 384
#define DM 256
#define NH 4
#define FF 1024
#define HIDN 512
#define NCLS 56
#define NPAIR (NN*(NN-1))   // 147072

typedef __attribute__((ext_vector_type(8))) short short8v;
typedef __attribute__((ext_vector_type(4))) float f32x4;
typedef __attribute__((ext_vector_type(16))) float f32x16;
typedef __attribute__((ext_vector_type(8))) unsigned short ushort8;
typedef __attribute__((ext_vector_type(4))) unsigned int uint4v;

static __device__ __forceinline__ unsigned short f2bf(float f) {
  unsigned u = __float_as_uint(f);
  unsigned r = u + 0x7fff + ((u >> 16) & 1);   // RNE
  return (unsigned short)(r >> 16);
}
static __device__ __forceinline__ float bf2f(unsigned short v) {
  return __uint_as_float(((unsigned)v) << 16);
}
static __device__ __forceinline__ unsigned cvt_pk_bf16(float lo, float hi) {
  unsigned r;
  asm("v_cvt_pk_bf16_f32 %0, %1, %2" : "=v"(r) : "v"(lo), "v"(hi));
  return r;
}
// C/D row for 32x32x16 MFMA (v7-verified): ml = (reg&3)+8*(reg>>2)+4*half
#define MLROW(reg, half) (((reg) & 3) + 8 * ((reg) >> 2) + 4 * (half))

// ===== pack ALL weights into 32x32x16 B-fragment order (bf16) ==============
__global__ __launch_bounds__(256)
void pack_all(const float* __restrict__ wi, const float* __restrict__ wo,
              const float* __restrict__ w1, const float* __restrict__ w2,
              const float* __restrict__ mw1, const float* __restrict__ mw2,
              unsigned short* __restrict__ wi_f, unsigned short* __restrict__ wo_f,
              unsigned short* __restrict__ w1_f, unsigned short* __restrict__ w2_f,
              unsigned short* __restrict__ mw1_f, unsigned short* __restrict__ mw2_f) {
  int y = blockIdx.y, z = blockIdx.z;
  int t = blockIdx.x * 256 + threadIdx.x;
  const float* src; unsigned short* dst; int K, N; long sS, sD;
  switch (y) {
    case 0: src = wi;  dst = wi_f;  K = 256;  N = 768;  sS = 256L*768;  sD = 196608; break;
    case 1: src = wo;  dst = wo_f;  K = 256;  N = 256;  sS = 256L*256;  sD = 65536;  break;
    case 2: src = w1;  dst = w1_f;  K = 256;  N = 1024; sS = 256L*1024; sD = 262144; break;
    case 3: src = w2;  dst = w2_f;  K = 1024; N = 256;  sS = 1024L*256; sD = 262144; break;
    case 4: src = mw1; dst = mw1_f; K = 256;  N = 512;  sS = 256L*512;  sD = 131072; break;
    default: {   // mw2 [512,56] -> Nt=2 padded to 64 cols, ks=32
      if (z || t >= 4096) return;
      int l = t & 63, nt = (t >> 6) & 1, ks = t >> 7;
      int kb = ks * 16 + ((l >> 5) * 8), n = nt * 32 + (l & 31);
      #pragma unroll
      for (int r = 0; r < 8; ++r) {
        float v = (n < NCLS) ? mw2[(size_t)(kb + r) * NCLS + n] : 0.f;
        mw2_f[(size_t)t * 8 + r] = f2bf(v);
      }
      return;
    }
  }
  int Nt = N >> 5;
  int total = (K >> 4) * Nt * 64;
  if (t >= total) return;
  src += z * sS; dst += z * sD;
  int l = t & 63;
  int rem = t >> 6;
  int nt = rem % Nt, ks = rem / Nt;
  int kb = ks * 16 + ((l >> 5) * 8), n = nt * 32 + (l & 31);
  #pragma unroll
  for (int r = 0; r < 8; ++r)
    dst[(size_t)t * 8 + r] = f2bf(src[(size_t)(kb + r) * N + n]);
}

// ===== init: node -> xbuf f32 + x_bf bf16 ===================================
__global__ __launch_bounds__(256)
void x_init(const float* __restrict__ node, float* __restrict__ xbuf,
            unsigned short* __restrict__ xbf) {
  int i = blockIdx.x * 256 + threadIdx.x;   // 98304
  float v = node[i];
  xbuf[i] = v;
  xbf[i] = f2bf(v);
}

// ===== QKV projection: x_bf @ wi + bi; writes QK row-major + V transposed ==
__global__ __launch_bounds__(256)
void qkv_mfma(const unsigned short* __restrict__ xbf, const unsigned short* __restrict__ wif,
              const float* __restrict__ bi, unsigned short* __restrict__ qk,
              unsigned short* __restrict__ vt) {
  int id = blockIdx.x * 4 + (threadIdx.x >> 6);   // 0..287 (12 mt x 24 nt)
  int lane = threadIdx.x & 63;
  int mt = id % 12, nt = id / 12;
  int col = lane & 31, half = lane >> 5;
  const unsigned short* asrc = xbf + (size_t)(mt * 32 + col) * 256 + half * 8;
  const unsigned short* bsrc = wif + ((size_t)nt * 64 + lane) * 8;
  f32x16 acc = {};
  #pragma unroll
  for (int ks = 0; ks < 16; ++ks) {
    short8v a = *reinterpret_cast<const short8v*>(asrc + ks * 16);
    short8v b = *reinterpret_cast<const short8v*>(bsrc + (size_t)ks * 24 * 512);
    acc = __builtin_amdgcn_mfma_f32_32x32x16_bf16(a, b, acc, 0, 0, 0);
  }
  int n = nt * 32 + col;
  float bb = bi[n];
  #pragma unroll
  for (int reg = 0; reg < 16; ++reg) {
    int row = mt * 32 + MLROW(reg, half);
    float v = acc[reg] + bb;
    if (n < 512) qk[(size_t)row * 512 + n] = f2bf(v);         // Q | K
    else         vt[(size_t)(n - 512) * 384 + row] = f2bf(v); // V^T [256][384]
  }
}

// ===== fused attention: S = QK^T/8 -> softmax -> O = P@V ===================
__global__ __launch_bounds__(256)
void fused_attn(const unsigned short* __restrict__ qk, const unsigned short* __restrict__ vt,
                unsigned short* __restrict__ attno) {
  __shared__ float S[64][385];
  __shared__ unsigned short P[64][392];
  int n0 = blockIdx.x * 64;
  int h = blockIdx.y;
  int wave = threadIdx.x >> 6, lane = threadIdx.x & 63;
  int col = lane & 31, half = lane >> 5;
  {
    int mt = wave & 1;
    const unsigned short* asrc = qk + (size_t)(n0 + mt * 32 + col) * 512 + h * 64 + half * 8;
    #pragma unroll
    for (int j = 0; j < 6; ++j) {
      int ntk = (wave >> 1) + j * 2;
      const unsigned short* bsrc = qk + (size_t)(ntk * 32 + col) * 512 + 256 + h * 64 + half * 8;
      f32x16 acc = {};
      #pragma unroll
      for (int ks = 0; ks < 4; ++ks) {
        short8v a = *reinterpret_cast<const short8v*>(asrc + ks * 16);
        short8v b = *reinterpret_cast<const short8v*>(bsrc + ks * 16);
        acc = __builtin_amdgcn_mfma_f32_32x32x16_bf16(a, b, acc, 0, 0, 0);
      }
      #pragma unroll
      for (int reg = 0; reg < 16; ++reg)
        S[mt * 32 + MLROW(reg, half)][ntk * 32 + col] = acc[reg] * 0.125f;
    }
  }
  __syncthreads();
  {
    int row = threadIdx.x >> 2, q = threadIdx.x & 3;
    float mx = -1e30f;
    #pragma unroll 8
    for (int c = 0; c < 96; ++c) mx = fmaxf(mx, S[row][q * 96 + c]);
    mx = fmaxf(mx, __shfl_xor(mx, 1));
    mx = fmaxf(mx, __shfl_xor(mx, 2));
    float sum = 0.f;
    #pragma unroll 8
    for (int c = 0; c < 96; ++c) {
      float e = __expf(S[row][q * 96 + c] - mx);
      S[row][q * 96 + c] = e;
      sum += e;
    }
    sum += __shfl_xor(sum, 1);
    sum += __shfl_xor(sum, 2);
    float inv = 1.0f / sum;
    #pragma unroll 8
    for (int c = 0; c < 96; ++c)
      P[row][q * 96 + c] = f2bf(S[row][q * 96 + c] * inv);
  }
  __syncthreads();
  {
    int mt = wave & 1, ntd = wave >> 1;
    const unsigned short* bsrc = vt + (size_t)(h * 64 + ntd * 32 + col) * 384 + half * 8;
    f32x16 acc = {};
    #pragma unroll
    for (int ks = 0; ks < 24; ++ks) {
      short8v a = *reinterpret_cast<const short8v*>(&P[mt * 32 + col][ks * 16 + half * 8]);
      short8v b = *reinterpret_cast<const short8v*>(bsrc + ks * 16);
      acc = __builtin_amdgcn_mfma_f32_32x32x16_bf16(a, b, acc, 0, 0, 0);
    }
    #pragma unroll
    for (int reg = 0; reg < 16; ++reg)
      attno[(size_t)(n0 + mt * 32 + MLROW(reg, half)) * 256 + h * 64 + ntd * 32 + col] =
          f2bf(acc[reg]);
  }
}

// ===== residual add + LayerNorm (one row per block); emits f32 + bf16 ======
__global__ __launch_bounds__(256)
void add_ln(float* __restrict__ x, unsigned short* __restrict__ xbf,
            const float* __restrict__ r,
            const float* __restrict__ g, const float* __restrict__ b) {
  int i = blockIdx.x, t = threadIdx.x;
  float v = x[(size_t)i * DM + t] + r[(size_t)i * DM + t];
  __shared__ float red[256];
  red[t] = v; __syncthreads();
  for (int s = 128; s > 0; s >>= 1) { if (t < s) red[t] += red[t + s]; __syncthreads(); }
  float mu = red[0] * (1.0f / DM); __syncthreads();
  float dv = v - mu;
  red[t] = dv * dv; __syncthreads();
  for (int s = 128; s > 0; s >>= 1) { if (t < s) red[t] += red[t + s]; __syncthreads(); }
  float var = red[0] * (1.0f / DM);
  float inv = rsqrtf(var + 1e-5f);
  float o = dv * inv * g[t] + b[t];
  x[(size_t)i * DM + t] = o;
  xbf[(size_t)i * DM + t] = f2bf(o);
}

// ===== generic MFMA GEMM, one wave per 32x32 tile ==========================
template<int OUT_BF16, int RELU, int NKS, int NT>
__global__ __launch_bounds__(256)
void mfma_gemm(const unsigned short* __restrict__ A, int lda, long sA,
               const unsigned short* __restrict__ Bfrag, long sB,
               const float* __restrict__ bias,
               float* __restrict__ Cf, unsigned short* __restrict__ Cb,
               int ldc, long sC, int Mt) {
  int id = blockIdx.x * 4 + (threadIdx.x >> 6);
  if (id >= Mt * NT) return;
  int lane = threadIdx.x & 63;
  int mt = id % Mt, nt = id / Mt;
  int z = blockIdx.z;
  int col = lane & 31, half = lane >> 5;
  const unsigned short* asrc = A + z * sA + (size_t)(mt * 32 + col) * lda + half * 8;
  const unsigned short* bsrc = Bfrag + z * sB + ((size_t)nt * 64 + lane) * 8;
  f32x16 acc = {};
  #pragma unroll
  for (int ks = 0; ks < NKS; ++ks) {
    short8v a = *reinterpret_cast<const short8v*>(asrc + ks * 16);
    short8v b = *reinterpret_cast<const short8v*>(bsrc + (size_t)ks * NT * 512);
    acc = __builtin_amdgcn_mfma_f32_32x32x16_bf16(a, b, acc, 0, 0, 0);
  }
  int n = nt * 32 + col;
  float bb = bias ? bias[n] : 0.f;
  #pragma unroll
  for (int reg = 0; reg < 16; ++reg) {
    int row = mt * 32 + MLROW(reg, half);
    float v = acc[reg] + bb;
    if (RELU) v = fmaxf(v, 0.f);
    if (OUT_BF16) Cb[z * sC + (size_t)row * ldc + n] = f2bf(v);
    else          Cf[z * sC + (size_t)row * ldc + n] = v;
  }
}

// ===== relation-head helpers ===============================================
__global__ __launch_bounds__(256)
void uv_fixup(const float* __restrict__ boxes, const float* __restrict__ w1,
              const float* __restrict__ b1,
              float* __restrict__ U, const float* __restrict__ V,
              unsigned short* __restrict__ Vbf) {
  int idx = blockIdx.x * 256 + threadIdx.x;   // NN*HIDN
  int i = idx >> 9, k = idx & 511;
  float u = U[idx] + b1[k], v = V[idx];
  #pragma unroll
  for (int c = 0; c < 4; ++c) {
    float bv = boxes[i * 4 + c];
    u += bv * w1[(size_t)(512 + c) * HIDN + k];
    v += bv * w1[(size_t)(516 + c) * HIDN + k];
  }
  U[idx] = u;
  Vbf[idx] = f2bf(v);
}

__global__ __launch_bounds__(256)
void pair_idx_kernel(float* __restrict__ out) {
  int p = blockIdx.x * 256 + threadIdx.x;
  if (p >= NPAIR) return;
  int i = p / (NN - 1);
  int r = p - i * (NN - 1);
  int j = r + (r >= i ? 1 : 0);
  out[2 * p + 0] = (float)i;
  out[2 * p + 1] = (float)j;
}

// pair MLP v7: 32x32x16, streamed B, build-once (r9: 47us)
__global__ __launch_bounds__(256)
void pair_mfma(const float* __restrict__ U, const unsigned short* __restrict__ Vbf,
               const unsigned short* __restrict__ w2frag,
               const float* __restrict__ b2, float* __restrict__ out) {
  int tid = threadIdx.x;
  int wave = tid >> 6;
  int lane = tid & 63;
  int bx = blockIdx.x;
  int i = bx / 3;
  int jt = (bx % 3) * 4 + wave;

  int col = lane & 31;
  int half = lane >> 5;
  int j_row = jt * 32 + col;

  const unsigned short* vsrc = Vbf + (size_t)j_row * HIDN + half * 8;
  const float* usrc = U + (size_t)i * HIDN + half * 8;
  const unsigned short* bsrc = w2frag + (size_t)lane * 8;

  f32x16 acc0 = {};
  f32x16 acc1 = {};
  #pragma unroll
  for (int ks = 0; ks < 32; ++ks) {
    ushort8 v8 = *reinterpret_cast<const ushort8*>(vsrc + ks * 16);
    float4 ua = *reinterpret_cast<const float4*>(usrc + ks * 16);
    float4 ub = *reinterpret_cast<const float4*>(usrc + ks * 16 + 4);
    short8v b0 = *reinterpret_cast<const short8v*>(bsrc + (size_t)(ks * 2 + 0) * 512);
    short8v b1 = *reinterpret_cast<const short8v*>(bsrc + (size_t)(ks * 2 + 1) * 512);
    float h0 = fmaxf(bf2f(v8[0]) + ua.x, 0.f);
    float h1 = fmaxf(bf2f(v8[1]) + ua.y, 0.f);
    float h2 = fmaxf(bf2f(v8[2]) + ua.z, 0.f);
    float h3 = fmaxf(bf2f(v8[3]) + ua.w, 0.f);
    float h4 = fmaxf(bf2f(v8[4]) + ub.x, 0.f);
    float h5 = fmaxf(bf2f(v8[5]) + ub.y, 0.f);
    float h6 = fmaxf(bf2f(v8[6]) + ub.z, 0.f);
    float h7 = fmaxf(bf2f(v8[7]) + ub.w, 0.f);
    uint4v pk;
    pk[0] = cvt_pk_bf16(h0, h1);
    pk[1] = cvt_pk_bf16(h2, h3);
    pk[2] = cvt_pk_bf16(h4, h5);
    pk[3] = cvt_pk_bf16(h6, h7);
    short8v a = *reinterpret_cast<short8v*>(&pk);
    acc0 = __builtin_amdgcn_mfma_f32_32x32x16_bf16(a, b0, acc0, 0, 0, 0);
    acc1 = __builtin_amdgcn_mfma_f32_32x32x16_bf16(a, b1, acc1, 0, 0, 0);
  }

  float b2v0 = b2[col];
  float b2v1 = (32 + col < NCLS) ? b2[32 + col] : 0.f;
  float* lg = out + 2 * (size_t)NPAIR;
  #pragma unroll
  for (int reg = 0; reg < 16; ++reg) {
    int jl = MLROW(reg, half);
    int j = jt * 32 + jl;
    if (j != i) {
      int p = i * (NN - 1) + (j > i ? j - 1 : j);
      float* row = lg + (size_t)p * NCLS;
      row[col] = acc0[reg] + b2v0;
      if (col < NCLS - 32) row[32 + col] = acc1[reg] + b2v1;
    }
  }
}

// ===========================================================================
extern "C" void kernel_launch(void* const* d_in, const int* in_sizes, int n_in,
                              void* d_out, int out_size, void* d_ws, size_t ws_size,
                              hipStream_t stream) {
  const float* node   = (const float*)d_in[0];
  const float* boxes  = (const float*)d_in[1];
  const float* w_in   = (const float*)d_in[2];
  const float* b_in   = (const float*)d_in[3];
  const float* w_out  = (const float*)d_in[4];
  const float* b_out  = (const float*)d_in[5];
  const float* fw1    = (const float*)d_in[6];
  const float* fb1    = (const float*)d_in[7];
  const float* fw2    = (const float*)d_in[8];
  const float* fb2    = (const float*)d_in[9];
  const float* ln1g   = (const float*)d_in[10];
  const float* ln1b   = (const float*)d_in[11];
  const float* ln2g   = (const float*)d_in[12];
  const float* ln2b   = (const float*)d_in[13];
  const float* mw1    = (const float*)d_in[14];
  const float* mb1    = (const float*)d_in[15];
  const float* mw2    = (const float*)d_in[16];
  const float* mb2    = (const float*)d_in[17];
  float* out = (float*)d_out;

  float* ws = (float*)d_ws;
  float* xbuf = ws;                    // 98304 f32
  float* proj = xbuf + 98304;          // 98304 f32
  float* U    = proj + 98304;          // 196608 f32
  float* V    = U + 196608;            // 196608 f32
  unsigned short* us = (unsigned short*)(V + 196608);
  unsigned short* x_bf   = us;             us += 98304;
  unsigned short* qk_bf  = us;             us += 196608;   // [384][512]
  unsigned short* vt_bf  = us;             us += 98304;    // [256][384]
  unsigned short* at_bf  = us;             us += 98304;    // [384][256]
  unsigned short* ffh_bf = us;             us += 393216;   // [384][1024]
  unsigned short* Vbf    = us;             us += 196608;   // [384][512]
  unsigned short* wi_f   = us;             us += 393216;   // 2 x 196608
  unsigned short* wo_f   = us;             us += 131072;   // 2 x 65536
  unsigned short* fw1_f  = us;             us += 524288;   // 2 x 262144
  unsigned short* fw2_f  = us;             us += 524288;   // 2 x 262144
  unsigned short* mw1_f  = us;             us += 262144;   // 2 x 131072
  unsigned short* w2_f   = us;             us += 32768;

  // one-time prep
  pack_all<<<dim3(128, 6, 2), 256, 0, stream>>>(w_in, w_out, fw1, fw2, mw1, mw2,
                                                wi_f, wo_f, fw1_f, fw2_f, mw1_f, w2_f);
  pair_idx_kernel<<<dim3((NPAIR + 255) / 256), 256, 0, stream>>>(out);
  x_init<<<dim3(384), 256, 0, stream>>>(node, xbuf, x_bf);

  for (int l = 0; l < 2; ++l) {
    qkv_mfma<<<dim3(72), 256, 0, stream>>>(x_bf, wi_f + (size_t)l * 196608,
                                           b_in + (size_t)l * 768, qk_bf, vt_bf);
    fused_attn<<<dim3(6, 4), 256, 0, stream>>>(qk_bf, vt_bf, at_bf);
    // proj = attno @ wo + bo   (f32 out, 24 blocks)
    mfma_gemm<0, 0, 16, 8><<<dim3(24), 256, 0, stream>>>(
        at_bf, 256, 0, wo_f + (size_t)l * 65536, 0, b_out + (size_t)l * 256,
        proj, nullptr, 256, 0, 12);
    add_ln<<<dim3(NN), 256, 0, stream>>>(xbuf, x_bf, proj,
                                         ln1g + (size_t)l * 256, ln1b + (size_t)l * 256);
    // FFN1 (relu, bf16 out, 96 blocks)
    mfma_gemm<1, 1, 16, 32><<<dim3(96), 256, 0, stream>>>(
        x_bf, 256, 0, fw1_f + (size_t)l * 262144, 0, fb1 + (size_t)l * 1024,
        nullptr, ffh_bf, 1024, 0, 12);
    // FFN2 (f32 out, 24 blocks)
    mfma_gemm<0, 0, 64, 8><<<dim3(24), 256, 0, stream>>>(
        ffh_bf, 1024, 0, fw2_f + (size_t)l * 262144, 0, fb2 + (size_t)l * 256,
        proj, nullptr, 256, 0, 12);
    add_ln<<<dim3(NN), 256, 0, stream>>>(xbuf, x_bf, proj,
                                         ln2g + (size_t)l * 256, ln2b + (size_t)l * 256);
  }

  // relation head: U,V = x @ mw1 halves (batched z=2), then fixup + pair GEMM
  mfma_gemm<0, 0, 16, 16><<<dim3(48, 1, 2), 256, 0, stream>>>(
      x_bf, 256, 0, mw1_f, 131072, nullptr, U, nullptr, 512, 196608, 12);
  uv_fixup<<<dim3(NN * HIDN / 256), 256, 0, stream>>>(boxes, mw1, mb1, U, V, Vbf);
  pair_mfma<<<dim3(1152), 256, 0, stream>>>(U, Vbf, w2_f, mb2, out);
}

// Round 12
// 129.595 us; speedup vs baseline: 2.8885x; 1.3408x over previous
//
#include <hip/hip_runtime.h>

#define NN 384
#define DM 256
#define NH 4
#define FF 1024
#define HIDN 512
#define NCLS 56
#define NPAIR (NN*(NN-1))   // 147072

typedef __attribute__((ext_vector_type(8))) short short8v;
typedef __attribute__((ext_vector_type(4))) float f32x4;
typedef __attribute__((ext_vector_type(16))) float f32x16;
typedef __attribute__((ext_vector_type(8))) unsigned short ushort8;
typedef __attribute__((ext_vector_type(4))) unsigned int uint4v;

static __device__ __forceinline__ unsigned short f2bf(float f) {
  unsigned u = __float_as_uint(f);
  unsigned r = u + 0x7fff + ((u >> 16) & 1);   // RNE
  return (unsigned short)(r >> 16);
}
static __device__ __forceinline__ float bf2f(unsigned short v) {
  return __uint_as_float(((unsigned)v) << 16);
}
static __device__ __forceinline__ unsigned cvt_pk_bf16(float lo, float hi) {
  unsigned r;
  asm("v_cvt_pk_bf16_f32 %0, %1, %2" : "=v"(r) : "v"(lo), "v"(hi));
  return r;
}
// C/D row for 32x32x16 MFMA (v7-verified): ml = (reg&3)+8*(reg>>2)+4*half
#define MLROW(reg, half) (((reg) & 3) + 8 * ((reg) >> 2) + 4 * (half))

// ===== pack ALL weights into 32x32x16 B-fragment order (bf16) ==============
__global__ __launch_bounds__(256)
void pack_all(const float* __restrict__ wi, const float* __restrict__ wo,
              const float* __restrict__ w1, const float* __restrict__ w2,
              const float* __restrict__ mw1, const float* __restrict__ mw2,
              unsigned short* __restrict__ wi_f, unsigned short* __restrict__ wo_f,
              unsigned short* __restrict__ w1_f, unsigned short* __restrict__ w2_f,
              unsigned short* __restrict__ mw1_f, unsigned short* __restrict__ mw2_f) {
  int y = blockIdx.y, z = blockIdx.z;
  int t = blockIdx.x * 256 + threadIdx.x;
  const float* src; unsigned short* dst; int K, N; long sS, sD;
  switch (y) {
    case 0: src = wi;  dst = wi_f;  K = 256;  N = 768;  sS = 256L*768;  sD = 196608; break;
    case 1: src = wo;  dst = wo_f;  K = 256;  N = 256;  sS = 256L*256;  sD = 65536;  break;
    case 2: src = w1;  dst = w1_f;  K = 256;  N = 1024; sS = 256L*1024; sD = 262144; break;
    case 3: src = w2;  dst = w2_f;  K = 1024; N = 256;  sS = 1024L*256; sD = 262144; break;
    case 4: src = mw1; dst = mw1_f; K = 256;  N = 512;  sS = 256L*512;  sD = 131072; break;
    default: {   // mw2 [512,56] -> Nt=2 padded to 64 cols, ks=32
      if (z || t >= 4096) return;
      int l = t & 63, nt = (t >> 6) & 1, ks = t >> 7;
      int kb = ks * 16 + ((l >> 5) * 8), n = nt * 32 + (l & 31);
      #pragma unroll
      for (int r = 0; r < 8; ++r) {
        float v = (n < NCLS) ? mw2[(size_t)(kb + r) * NCLS + n] : 0.f;
        mw2_f[(size_t)t * 8 + r] = f2bf(v);
      }
      return;
    }
  }
  int Nt = N >> 5;
  int total = (K >> 4) * Nt * 64;
  if (t >= total) return;
  src += z * sS; dst += z * sD;
  int l = t & 63;
  int rem = t >> 6;
  int nt = rem % Nt, ks = rem / Nt;
  int kb = ks * 16 + ((l >> 5) * 8), n = nt * 32 + (l & 31);
  #pragma unroll
  for (int r = 0; r < 8; ++r)
    dst[(size_t)t * 8 + r] = f2bf(src[(size_t)(kb + r) * N + n]);
}

// ===== init: node -> xbuf f32 + x_bf bf16 ===================================
__global__ __launch_bounds__(256)
void x_init(const float* __restrict__ node, float* __restrict__ xbuf,
            unsigned short* __restrict__ xbf) {
  int i = blockIdx.x * 256 + threadIdx.x;   // 98304
  float v = node[i];
  xbuf[i] = v;
  xbf[i] = f2bf(v);
}

// ===== QKV projection: x_bf @ wi + bi; writes QK row-major + V transposed ==
__global__ __launch_bounds__(128)
void qkv_mfma(const unsigned short* __restrict__ xbf, const unsigned short* __restrict__ wif,
              const float* __restrict__ bi, unsigned short* __restrict__ qk,
              unsigned short* __restrict__ vt) {
  int id = blockIdx.x * 2 + (threadIdx.x >> 6);   // 0..287 (12 mt x 24 nt)
  int lane = threadIdx.x & 63;
  int mt = id % 12, nt = id / 12;
  int col = lane & 31, half = lane >> 5;
  const unsigned short* asrc = xbf + (size_t)(mt * 32 + col) * 256 + half * 8;
  const unsigned short* bsrc = wif + ((size_t)nt * 64 + lane) * 8;
  f32x16 acc = {};
  #pragma unroll
  for (int ks = 0; ks < 16; ++ks) {
    short8v a = *reinterpret_cast<const short8v*>(asrc + ks * 16);
    short8v b = *reinterpret_cast<const short8v*>(bsrc + (size_t)ks * 24 * 512);
    acc = __builtin_amdgcn_mfma_f32_32x32x16_bf16(a, b, acc, 0, 0, 0);
  }
  int n = nt * 32 + col;
  float bb = bi[n];
  #pragma unroll
  for (int reg = 0; reg < 16; ++reg) {
    int row = mt * 32 + MLROW(reg, half);
    float v = acc[reg] + bb;
    if (n < 512) qk[(size_t)row * 512 + n] = f2bf(v);         // Q | K
    else         vt[(size_t)(n - 512) * 384 + row] = f2bf(v); // V^T [256][384]
  }
}

// ===== fused attention v2: 32-row tiles, 48 blocks =========================
__global__ __launch_bounds__(256)
void fused_attn(const unsigned short* __restrict__ qk, const unsigned short* __restrict__ vt,
                unsigned short* __restrict__ attno) {
  __shared__ float S[32][385];
  __shared__ unsigned short P[32][392];
  int n0 = blockIdx.x * 32;
  int h = blockIdx.y;
  int wave = threadIdx.x >> 6, lane = threadIdx.x & 63;
  int col = lane & 31, half = lane >> 5;
  // phase 1: S = QK^T / 8  (each wave: 3 ntk col-tiles)
  {
    const unsigned short* asrc = qk + (size_t)(n0 + col) * 512 + h * 64 + half * 8;
    #pragma unroll
    for (int jj = 0; jj < 3; ++jj) {
      int ntk = wave * 3 + jj;
      const unsigned short* bsrc = qk + (size_t)(ntk * 32 + col) * 512 + 256 + h * 64 + half * 8;
      f32x16 acc = {};
      #pragma unroll
      for (int ks = 0; ks < 4; ++ks) {
        short8v a = *reinterpret_cast<const short8v*>(asrc + ks * 16);
        short8v b = *reinterpret_cast<const short8v*>(bsrc + ks * 16);
        acc = __builtin_amdgcn_mfma_f32_32x32x16_bf16(a, b, acc, 0, 0, 0);
      }
      #pragma unroll
      for (int reg = 0; reg < 16; ++reg)
        S[MLROW(reg, half)][ntk * 32 + col] = acc[reg] * 0.125f;
    }
  }
  __syncthreads();
  // phase 2: softmax (8 threads per row)
  {
    int row = threadIdx.x >> 3, q = threadIdx.x & 7;
    float mx = -1e30f;
    #pragma unroll 8
    for (int c = 0; c < 48; ++c) mx = fmaxf(mx, S[row][q * 48 + c]);
    mx = fmaxf(mx, __shfl_xor(mx, 1));
    mx = fmaxf(mx, __shfl_xor(mx, 2));
    mx = fmaxf(mx, __shfl_xor(mx, 4));
    float sum = 0.f;
    #pragma unroll 8
    for (int c = 0; c < 48; ++c) {
      float e = __expf(S[row][q * 48 + c] - mx);
      S[row][q * 48 + c] = e;
      sum += e;
    }
    sum += __shfl_xor(sum, 1);
    sum += __shfl_xor(sum, 2);
    sum += __shfl_xor(sum, 4);
    float inv = 1.0f / sum;
    #pragma unroll 8
    for (int c = 0; c < 48; ++c)
      P[row][q * 48 + c] = f2bf(S[row][q * 48 + c] * inv);
  }
  __syncthreads();
  // phase 3: O = P @ V  (waves 0-1, one 32-d tile each)
  if (wave < 2) {
    int ntd = wave;
    const unsigned short* bsrc = vt + (size_t)(h * 64 + ntd * 32 + col) * 384 + half * 8;
    f32x16 acc = {};
    #pragma unroll
    for (int ks = 0; ks < 24; ++ks) {
      short8v a = *reinterpret_cast<const short8v*>(&P[col][ks * 16 + half * 8]);
      short8v b = *reinterpret_cast<const short8v*>(bsrc + ks * 16);
      acc = __builtin_amdgcn_mfma_f32_32x32x16_bf16(a, b, acc, 0, 0, 0);
    }
    #pragma unroll
    for (int reg = 0; reg < 16; ++reg)
      attno[(size_t)(n0 + MLROW(reg, half)) * 256 + h * 64 + ntd * 32 + col] =
          f2bf(acc[reg]);
  }
}

// ===== residual add + LayerNorm (one row per block); emits f32 + bf16 ======
__global__ __launch_bounds__(256)
void add_ln(float* __restrict__ x, unsigned short* __restrict__ xbf,
            const float* __restrict__ r,
            const float* __restrict__ g, const float* __restrict__ b) {
  int i = blockIdx.x, t = threadIdx.x;
  float v = x[(size_t)i * DM + t] + r[(size_t)i * DM + t];
  __shared__ float red[256];
  red[t] = v; __syncthreads();
  for (int s = 128; s > 0; s >>= 1) { if (t < s) red[t] += red[t + s]; __syncthreads(); }
  float mu = red[0] * (1.0f / DM); __syncthreads();
  float dv = v - mu;
  red[t] = dv * dv; __syncthreads();
  for (int s = 128; s > 0; s >>= 1) { if (t < s) red[t] += red[t + s]; __syncthreads(); }
  float var = red[0] * (1.0f / DM);
  float inv = rsqrtf(var + 1e-5f);
  float o = dv * inv * g[t] + b[t];
  x[(size_t)i * DM + t] = o;
  xbf[(size_t)i * DM + t] = f2bf(o);
}

// ===== generic MFMA GEMM, one wave per 32x32 tile (waves/block from dim) ===
template<int OUT_BF16, int RELU, int NKS, int NT>
__global__ void mfma_gemm(const unsigned short* __restrict__ A, int lda, long sA,
               const unsigned short* __restrict__ Bfrag, long sB,
               const float* __restrict__ bias,
               float* __restrict__ Cf, unsigned short* __restrict__ Cb,
               int ldc, long sC, int Mt) {
  int id = blockIdx.x * (blockDim.x >> 6) + (threadIdx.x >> 6);
  if (id >= Mt * NT) return;
  int lane = threadIdx.x & 63;
  int mt = id % Mt, nt = id / Mt;
  int z = blockIdx.z;
  int col = lane & 31, half = lane >> 5;
  const unsigned short* asrc = A + z * sA + (size_t)(mt * 32 + col) * lda + half * 8;
  const unsigned short* bsrc = Bfrag + z * sB + ((size_t)nt * 64 + lane) * 8;
  f32x16 acc = {};
  #pragma unroll
  for (int ks = 0; ks < NKS; ++ks) {
    short8v a = *reinterpret_cast<const short8v*>(asrc + ks * 16);
    short8v b = *reinterpret_cast<const short8v*>(bsrc + (size_t)ks * NT * 512);
    acc = __builtin_amdgcn_mfma_f32_32x32x16_bf16(a, b, acc, 0, 0, 0);
  }
  int n = nt * 32 + col;
  float bb = bias ? bias[n] : 0.f;
  #pragma unroll
  for (int reg = 0; reg < 16; ++reg) {
    int row = mt * 32 + MLROW(reg, half);
    float v = acc[reg] + bb;
    if (RELU) v = fmaxf(v, 0.f);
    if (OUT_BF16) Cb[z * sC + (size_t)row * ldc + n] = f2bf(v);
    else          Cf[z * sC + (size_t)row * ldc + n] = v;
  }
}

// ===== UV GEMM with fused box/bias epilogue ================================
// z=0: U[row][n] = (x@mw1_lo)[row][n] + b1[n] + boxes[row]·mw1[512:516][n]  (f32)
// z=1: Vbf[row][n] = bf16((x@mw1_hi)[row][n] + boxes[row]·mw1[516:520][n])
__global__ __launch_bounds__(128)
void uv_gemm(const unsigned short* __restrict__ xbf, const unsigned short* __restrict__ mw1f,
             const float* __restrict__ mw1, const float* __restrict__ b1,
             const float* __restrict__ boxes,
             float* __restrict__ U, unsigned short* __restrict__ Vbf) {
  int id = blockIdx.x * 2 + (threadIdx.x >> 6);   // 0..191 (12 mt x 16 nt)
  int lane = threadIdx.x & 63;
  int z = blockIdx.z;
  int mt = id % 12, nt = id / 12;
  int col = lane & 31, half = lane >> 5;
  const unsigned short* asrc = xbf + (size_t)(mt * 32 + col) * 256 + half * 8;
  const unsigned short* bsrc = mw1f + (size_t)z * 131072 + ((size_t)nt * 64 + lane) * 8;
  f32x16 acc = {};
  #pragma unroll
  for (int ks = 0; ks < 16; ++ks) {
    short8v a = *reinterpret_cast<const short8v*>(asrc + ks * 16);
    short8v b = *reinterpret_cast<const short8v*>(bsrc + (size_t)ks * 16 * 512);
    acc = __builtin_amdgcn_mfma_f32_32x32x16_bf16(a, b, acc, 0, 0, 0);
  }
  int n = nt * 32 + col;
  float w0 = mw1[(size_t)(512 + z * 4 + 0) * HIDN + n];
  float w1r = mw1[(size_t)(512 + z * 4 + 1) * HIDN + n];
  float w2r = mw1[(size_t)(512 + z * 4 + 2) * HIDN + n];
  float w3 = mw1[(size_t)(512 + z * 4 + 3) * HIDN + n];
  float bb = (z == 0) ? b1[n] : 0.f;
  #pragma unroll
  for (int reg = 0; reg < 16; ++reg) {
    int row = mt * 32 + MLROW(reg, half);
    const float* bx = boxes + row * 4;
    float v = acc[reg] + bb + bx[0] * w0 + bx[1] * w1r + bx[2] * w2r + bx[3] * w3;
    if (z == 0) U[(size_t)row * HIDN + n] = v;
    else        Vbf[(size_t)row * HIDN + n] = f2bf(v);
  }
}

// ===== pair indices output =================================================
__global__ __launch_bounds__(256)
void pair_idx_kernel(float* __restrict__ out) {
  int p = blockIdx.x * 256 + threadIdx.x;
  if (p >= NPAIR) return;
  int i = p / (NN - 1);
  int r = p - i * (NN - 1);
  int j = r + (r >= i ? 1 : 0);
  out[2 * p + 0] = (float)i;
  out[2 * p + 1] = (float)j;
}

// ===== pair MLP v8: 2 i's per straight-line wave task ======================
// Wave = (i-pair, jt). B/V loads + bf16 decode shared by both i's -> halves
// L2 streaming vs v7 and doubles per-iteration ILP. No loop-carried frags.
__global__ __launch_bounds__(128)
void pair_mfma(const float* __restrict__ U, const unsigned short* __restrict__ Vbf,
               const unsigned short* __restrict__ w2frag,
               const float* __restrict__ b2, float* __restrict__ out) {
  int task = blockIdx.x * 2 + (threadIdx.x >> 6);   // 0..2303
  int lane = threadIdx.x & 63;
  int ip = task / 12, jt = task % 12;
  int i0 = ip * 2;
  int col = lane & 31, half = lane >> 5;
  int j_row = jt * 32 + col;

  const unsigned short* vsrc = Vbf + (size_t)j_row * HIDN + half * 8;
  const float* u0 = U + (size_t)i0 * HIDN + half * 8;
  const float* u1 = u0 + HIDN;
  const unsigned short* bsrc = w2frag + (size_t)lane * 8;

  f32x16 acc00 = {}, acc01 = {}, acc10 = {}, acc11 = {};
  #pragma unroll
  for (int ks = 0; ks < 32; ++ks) {
    ushort8 v8 = *reinterpret_cast<const ushort8*>(vsrc + ks * 16);
    short8v b0 = *reinterpret_cast<const short8v*>(bsrc + (size_t)(ks * 2 + 0) * 512);
    short8v b1v = *reinterpret_cast<const short8v*>(bsrc + (size_t)(ks * 2 + 1) * 512);
    float4 ua0 = *reinterpret_cast<const float4*>(u0 + ks * 16);
    float4 ub0 = *reinterpret_cast<const float4*>(u0 + ks * 16 + 4);
    float4 ua1 = *reinterpret_cast<const float4*>(u1 + ks * 16);
    float4 ub1 = *reinterpret_cast<const float4*>(u1 + ks * 16 + 4);
    float v0 = bf2f(v8[0]), v1 = bf2f(v8[1]), v2 = bf2f(v8[2]), v3 = bf2f(v8[3]);
    float v4 = bf2f(v8[4]), v5 = bf2f(v8[5]), v6 = bf2f(v8[6]), v7 = bf2f(v8[7]);
    uint4v pk0;
    pk0[0] = cvt_pk_bf16(fmaxf(v0 + ua0.x, 0.f), fmaxf(v1 + ua0.y, 0.f));
    pk0[1] = cvt_pk_bf16(fmaxf(v2 + ua0.z, 0.f), fmaxf(v3 + ua0.w, 0.f));
    pk0[2] = cvt_pk_bf16(fmaxf(v4 + ub0.x, 0.f), fmaxf(v5 + ub0.y, 0.f));
    pk0[3] = cvt_pk_bf16(fmaxf(v6 + ub0.z, 0.f), fmaxf(v7 + ub0.w, 0.f));
    short8v a0 = *reinterpret_cast<short8v*>(&pk0);
    acc00 = __builtin_amdgcn_mfma_f32_32x32x16_bf16(a0, b0, acc00, 0, 0, 0);
    acc01 = __builtin_amdgcn_mfma_f32_32x32x16_bf16(a0, b1v, acc01, 0, 0, 0);
    uint4v pk1;
    pk1[0] = cvt_pk_bf16(fmaxf(v0 + ua1.x, 0.f), fmaxf(v1 + ua1.y, 0.f));
    pk1[1] = cvt_pk_bf16(fmaxf(v2 + ua1.z, 0.f), fmaxf(v3 + ua1.w, 0.f));
    pk1[2] = cvt_pk_bf16(fmaxf(v4 + ub1.x, 0.f), fmaxf(v5 + ub1.y, 0.f));
    pk1[3] = cvt_pk_bf16(fmaxf(v6 + ub1.z, 0.f), fmaxf(v7 + ub1.w, 0.f));
    short8v a1 = *reinterpret_cast<short8v*>(&pk1);
    acc10 = __builtin_amdgcn_mfma_f32_32x32x16_bf16(a1, b0, acc10, 0, 0, 0);
    acc11 = __builtin_amdgcn_mfma_f32_32x32x16_bf16(a1, b1v, acc11, 0, 0, 0);
  }

  float b2v0 = b2[col];
  float b2v1 = (32 + col < NCLS) ? b2[32 + col] : 0.f;
  float* lg = out + 2 * (size_t)NPAIR;
  int i1 = i0 + 1;
  #pragma unroll
  for (int reg = 0; reg < 16; ++reg) {
    int j = jt * 32 + MLROW(reg, half);
    if (j != i0) {
      int p = i0 * (NN - 1) + (j > i0 ? j - 1 : j);
      float* row = lg + (size_t)p * NCLS;
      row[col] = acc00[reg] + b2v0;
      if (col < NCLS - 32) row[32 + col] = acc01[reg] + b2v1;
    }
    if (j != i1) {
      int p = i1 * (NN - 1) + (j > i1 ? j - 1 : j);
      float* row = lg + (size_t)p * NCLS;
      row[col] = acc10[reg] + b2v0;
      if (col < NCLS - 32) row[32 + col] = acc11[reg] + b2v1;
    }
  }
}

// ===========================================================================
extern "C" void kernel_launch(void* const* d_in, const int* in_sizes, int n_in,
                              void* d_out, int out_size, void* d_ws, size_t ws_size,
                              hipStream_t stream) {
  const float* node   = (const float*)d_in[0];
  const float* boxes  = (const float*)d_in[1];
  const float* w_in   = (const float*)d_in[2];
  const float* b_in   = (const float*)d_in[3];
  const float* w_out  = (const float*)d_in[4];
  const float* b_out  = (const float*)d_in[5];
  const float* fw1    = (const float*)d_in[6];
  const float* fb1    = (const float*)d_in[7];
  const float* fw2    = (const float*)d_in[8];
  const float* fb2    = (const float*)d_in[9];
  const float* ln1g   = (const float*)d_in[10];
  const float* ln1b   = (const float*)d_in[11];
  const float* ln2g   = (const float*)d_in[12];
  const float* ln2b   = (const float*)d_in[13];
  const float* mw1    = (const float*)d_in[14];
  const float* mb1    = (const float*)d_in[15];
  const float* mw2    = (const float*)d_in[16];
  const float* mb2    = (const float*)d_in[17];
  float* out = (float*)d_out;

  float* ws = (float*)d_ws;
  float* xbuf = ws;                    // 98304 f32
  float* proj = xbuf + 98304;          // 98304 f32
  float* U    = proj + 98304;          // 196608 f32
  unsigned short* us = (unsigned short*)(U + 196608);
  unsigned short* x_bf   = us;             us += 98304;
  unsigned short* qk_bf  = us;             us += 196608;   // [384][512]
  unsigned short* vt_bf  = us;             us += 98304;    // [256][384]
  unsigned short* at_bf  = us;             us += 98304;    // [384][256]
  unsigned short* ffh_bf = us;             us += 393216;   // [384][1024]
  unsigned short* Vbf    = us;             us += 196608;   // [384][512]
  unsigned short* wi_f   = us;             us += 393216;   // 2 x 196608
  unsigned short* wo_f   = us;             us += 131072;   // 2 x 65536
  unsigned short* fw1_f  = us;             us += 524288;   // 2 x 262144
  unsigned short* fw2_f  = us;             us += 524288;   // 2 x 262144
  unsigned short* mw1_f  = us;             us += 262144;   // 2 x 131072
  unsigned short* w2_f   = us;             us += 32768;

  // one-time prep
  pack_all<<<dim3(128, 6, 2), 256, 0, stream>>>(w_in, w_out, fw1, fw2, mw1, mw2,
                                                wi_f, wo_f, fw1_f, fw2_f, mw1_f, w2_f);
  pair_idx_kernel<<<dim3((NPAIR + 255) / 256), 256, 0, stream>>>(out);
  x_init<<<dim3(384), 256, 0, stream>>>(node, xbuf, x_bf);

  for (int l = 0; l < 2; ++l) {
    qkv_mfma<<<dim3(144), 128, 0, stream>>>(x_bf, wi_f + (size_t)l * 196608,
                                            b_in + (size_t)l * 768, qk_bf, vt_bf);
    fused_attn<<<dim3(12, 4), 256, 0, stream>>>(qk_bf, vt_bf, at_bf);
    // proj = attno @ wo + bo   (f32 out, 96 wave-tiles -> 48 blocks)
    mfma_gemm<0, 0, 16, 8><<<dim3(48), 128, 0, stream>>>(
        at_bf, 256, 0, wo_f + (size_t)l * 65536, 0, b_out + (size_t)l * 256,
        proj, nullptr, 256, 0, 12);
    add_ln<<<dim3(NN), 256, 0, stream>>>(xbuf, x_bf, proj,
                                         ln1g + (size_t)l * 256, ln1b + (size_t)l * 256);
    // FFN1 (relu, bf16 out, 384 wave-tiles -> 192 blocks)
    mfma_gemm<1, 1, 16, 32><<<dim3(192), 128, 0, stream>>>(
        x_bf, 256, 0, fw1_f + (size_t)l * 262144, 0, fb1 + (size_t)l * 1024,
        nullptr, ffh_bf, 1024, 0, 12);
    // FFN2 (f32 out, 96 wave-tiles -> 48 blocks)
    mfma_gemm<0, 0, 64, 8><<<dim3(48), 128, 0, stream>>>(
        ffh_bf, 1024, 0, fw2_f + (size_t)l * 262144, 0, fb2 + (size_t)l * 256,
        proj, nullptr, 256, 0, 12);
    add_ln<<<dim3(NN), 256, 0, stream>>>(xbuf, x_bf, proj,
                                         ln2g + (size_t)l * 256, ln2b + (size_t)l * 256);
  }

  // relation head: fused UV GEMM (+box/bias epilogue), then pair GEMM
  uv_gemm<<<dim3(96, 1, 2), 128, 0, stream>>>(x_bf, mw1_f, mw1, mb1, boxes, U, Vbf);
  pair_mfma<<<dim3(1152), 128, 0, stream>>>(U, Vbf, w2_f, mb2, out);
}